// Round 14
// baseline (1776.398 us; speedup 1.0000x reference)
//
#include <hip/hip_runtime.h>

#define HW    4096
#define DIMC  512
#define MEDC  1024
#define HRC   256
#define HSC   256
#define NBATCH 16

typedef __attribute__((ext_vector_type(8))) short bf16x8;
typedef __attribute__((ext_vector_type(4))) float f32x4;

// ---------------- workspace layout (floats) ----------------
static const size_t R1_OFF    = 0;
static const size_t XT_OFF    = 8388608;
static const size_t WCONV_OFF = 25165824;
static const size_t WR1_OFF   = 25755648;
static const size_t WRC_OFF   = 25821184;
static const size_t XP_OFF    = 0;
static const size_t WB1_OFF   = 67108864;
static const size_t WB2_OFF   = 67371008;
static const size_t MEAN_OFF  = 67633152;
static const size_t AGG_OFF   = MEAN_OFF + 4096;
static const size_t TAP_OFF   = AGG_OFF + 36864;
static const size_t ROUTE_OFF = TAP_OFF + 36864;
static const size_t SR_OFF    = ROUTE_OFF + 65536;
static const size_t WS_END    = SR_OFF + 65536;

__device__ __forceinline__ unsigned short f2bf(float f) {
  unsigned u = __float_as_uint(f);
  unsigned r = (u + 0x7fffu + ((u >> 16) & 1u)) >> 16;
  return (unsigned short)r;
}

// ---------------- generic f32 -> bf16 elementwise ----------------
__global__ __launch_bounds__(256) void cvt_bf16(
    const float* __restrict__ src, unsigned short* __restrict__ dst, int n)
{
  int i = blockIdx.x * 256 + threadIdx.x;
  if (i < n) dst[i] = f2bf(src[i]);
}

// ---------------- x [b][c][4096] f32 -> xT [b][pix][512] bf16 ----------------
__global__ __launch_bounds__(256) void xpose_bf16(
    const float* __restrict__ x, unsigned short* __restrict__ xT)
{
  __shared__ unsigned short T[32][33];
  const int tid = threadIdx.x;
  const int p0 = blockIdx.x * 32, c0 = blockIdx.y * 32, bb = blockIdx.z;
#pragma unroll
  for (int i = 0; i < 4; i++) {
    int idx = i * 256 + tid;
    int c_l = idx >> 5, p_l = idx & 31;
    T[c_l][p_l] = f2bf(x[((size_t)(bb * DIMC + c0 + c_l)) * HW + p0 + p_l]);
  }
  __syncthreads();
#pragma unroll
  for (int i = 0; i < 4; i++) {
    int idx = i * 256 + tid;
    int p_l = idx >> 5, c_l = idx & 31;
    xT[((size_t)bb * HW + p0 + p_l) * DIMC + c0 + c_l] = T[c_l][p_l];
  }
}

// ---------------- sp1w [o][c][9] f32 -> wconv [t][o][c] bf16 ----------------
__global__ __launch_bounds__(256) void wconv_bf16(
    const float* __restrict__ w, unsigned short* __restrict__ wbf)
{
  int idx = blockIdx.x * 256 + threadIdx.x;
  if (idx < HSC * DIMC) {
#pragma unroll
    for (int t = 0; t < 9; t++)
      wbf[(size_t)t * (HSC * DIMC) + idx] = f2bf(w[(size_t)idx * 9 + t]);
  }
}

// ---------------- bf16 MFMA GEMM, 128 pix x 128 n tile, 4 waves ----------------
template<int EPI, int ASRC>
__global__ __launch_bounds__(256) void gemm_bf16(
    const void* __restrict__ Aptr, const unsigned short* __restrict__ Wb,
    const float* __restrict__ bias, float* __restrict__ Cf,
    unsigned short* __restrict__ Cb, float* __restrict__ meansum,
    const float* __restrict__ star_scale, const float* __restrict__ star_bias,
    int K, int Ntot)
{
  __shared__ __align__(16) unsigned short As[128 * 40];
  __shared__ __align__(16) unsigned short Bs[128 * 40];
  const int tid = threadIdx.x;
  const int pix0 = blockIdx.x * 128;
  const int n0g = blockIdx.y * 128;
  const int bb = blockIdx.z;
  const int wid = tid >> 6, lane = tid & 63;
  const int lo = lane & 15, hi = lane >> 4;
  const int wm = wid >> 1, wn = wid & 1;

  f32x4 acc[4][4];
#pragma unroll
  for (int mi = 0; mi < 4; mi++)
#pragma unroll
    for (int ni = 0; ni < 4; ni++) acc[mi][ni] = (f32x4){0.f, 0.f, 0.f, 0.f};

  const int nsteps = K >> 5;
  for (int s = 0; s < nsteps; s++) {
    const int c0 = s * 32;
    if (ASRC == 0) {
      const unsigned short* AT = (const unsigned short*)Aptr;
#pragma unroll
      for (int it = 0; it < 2; it++) {
        int idx = it * 256 + tid;
        int p = idx >> 2, co = (idx & 3) * 8;
        uint4 v = *(const uint4*)&AT[((size_t)bb * HW + pix0 + p) * K + c0 + co];
        *(uint4*)&As[p * 40 + co] = v;
      }
    } else {
      const float* Af = (const float*)Aptr;
#pragma unroll
      for (int it = 0; it < 4; it++) {
        int idx = it * 256 + tid;               // 0..1023
        int k_l = idx >> 5, p4 = (idx & 31) * 4;
        float4 v = *(const float4*)&Af[((size_t)bb * K + c0 + k_l) * HW + pix0 + p4];
        As[(p4 + 0) * 40 + k_l] = f2bf(v.x);
        As[(p4 + 1) * 40 + k_l] = f2bf(v.y);
        As[(p4 + 2) * 40 + k_l] = f2bf(v.z);
        As[(p4 + 3) * 40 + k_l] = f2bf(v.w);
      }
    }
#pragma unroll
    for (int it = 0; it < 2; it++) {
      int idx = it * 256 + tid;
      int o = idx >> 2, co = (idx & 3) * 8;
      uint4 v = *(const uint4*)&Wb[(size_t)(n0g + o) * K + c0 + co];
      *(uint4*)&Bs[o * 40 + co] = v;
    }
    __syncthreads();

    bf16x8 a[4], bq[4];
#pragma unroll
    for (int mi = 0; mi < 4; mi++)
      a[mi] = *(const bf16x8*)&As[(wm * 64 + mi * 16 + lo) * 40 + hi * 8];
#pragma unroll
    for (int ni = 0; ni < 4; ni++)
      bq[ni] = *(const bf16x8*)&Bs[(wn * 64 + ni * 16 + lo) * 40 + hi * 8];
#pragma unroll
    for (int mi = 0; mi < 4; mi++)
#pragma unroll
      for (int ni = 0; ni < 4; ni++)
        acc[mi][ni] = __builtin_amdgcn_mfma_f32_16x16x32_bf16(a[mi], bq[ni], acc[mi][ni], 0, 0, 0);
    __syncthreads();
  }

  if (EPI == 3) {
#pragma unroll
    for (int ni = 0; ni < 4; ni++) {
      const int n = n0g + wn * 64 + ni * 16 + lo;
      const float bia = bias[n];
      float T = 0.f;
#pragma unroll
      for (int mi = 0; mi < 4; mi++)
#pragma unroll
        for (int r = 0; r < 4; r++)
          T += fmaxf(acc[mi][ni][r] + bia, 0.f);
      T += __shfl_xor(T, 16);
      T += __shfl_xor(T, 32);
      if (hi == 0) atomicAdd(&meansum[bb * Ntot + n], T);
    }
    return;
  }

  if (EPI == 1) {
#pragma unroll
    for (int ni = 0; ni < 4; ni++) {
      const int n = n0g + wn * 64 + ni * 16 + lo;
      const float bia = bias[n];
#pragma unroll
      for (int mi = 0; mi < 4; mi++)
#pragma unroll
        for (int r = 0; r < 4; r++) {
          const int pix = pix0 + wm * 64 + mi * 16 + hi * 4 + r;
          Cb[((size_t)bb * HW + pix) * Ntot + n] = f2bf(fmaxf(acc[mi][ni][r] + bia, 0.f));
        }
    }
    return;
  }

  float ss = 1.f, sb = 0.f;
  if (EPI == 2) { ss = star_scale[0]; sb = star_bias[0]; }
#pragma unroll
  for (int ni = 0; ni < 4; ni++) {
    const int n = n0g + wn * 64 + ni * 16 + lo;
#pragma unroll
    for (int mi = 0; mi < 4; mi++) {
      const int pixb = pix0 + wm * 64 + mi * 16 + hi * 4;
      float4 v;
      float* vv = (float*)&v;
#pragma unroll
      for (int r = 0; r < 4; r++) {
        float t = acc[mi][ni][r];
        if (EPI == 2) { t = fmaxf(t, 0.f); t = ss * t * t + sb; }
        vv[r] = t;
      }
      *(float4*)&Cf[((size_t)bb * Ntot + n) * HW + pixb] = v;
    }
  }
}

// ---------------- sp_fc1 3x3 conv: halo-LDS implicit GEMM + relu + aggregates ----------------
// Per c-chunk: stage 4-row x 66-col x 32-c zero-padded halo ONCE; 9 taps read
// tap-shifted A-fragments directly from the halo. B staged per (tap, chunk).
__global__ __launch_bounds__(256) void conv3_mfma(
    const unsigned short* __restrict__ xT, const unsigned short* __restrict__ wbf,
    const float* __restrict__ bias, float* __restrict__ agg)
{
  __shared__ __align__(16) unsigned short Xs[4 * 66 * 40];  // 21120 B
  __shared__ __align__(16) unsigned short Bs[128 * 40];     // 10240 B
  const int tid = threadIdx.x;
  const int bx = blockIdx.x;
  const int n0g = blockIdx.y * 128;
  const int bb = blockIdx.z;
  const int h0 = bx * 2;
  const int wid = tid >> 6;
  const int lane = tid & 63;
  const int lo = lane & 15, hi = lane >> 4;
  const int wm = wid >> 1;
  const int wn = wid & 1;

  f32x4 acc[4][4];
#pragma unroll
  for (int mi = 0; mi < 4; mi++)
#pragma unroll
    for (int ni = 0; ni < 4; ni++) acc[mi][ni] = (f32x4){0.f, 0.f, 0.f, 0.f};

  for (int ch = 0; ch < 16; ch++) {
    const int c0 = ch * 32;
    // stage A halo (1056 uint4): rows h0-1..h0+2, cols -1..64, zero-padded
#pragma unroll
    for (int it = 0; it < 5; it++) {
      int idx = it * 256 + tid;
      if (idx < 1056) {
        int pos = idx >> 2, q = idx & 3;
        int r = pos / 66, cc = pos - r * 66;
        int h = h0 + r - 1, col = cc - 1;
        uint4 v = make_uint4(0u, 0u, 0u, 0u);
        if (h >= 0 && h < 64 && col >= 0 && col < 64)
          v = *(const uint4*)&xT[((size_t)bb * HW + h * 64 + col) * DIMC + c0 + q * 8];
        *(uint4*)&Xs[pos * 40 + q * 8] = v;
      }
    }
#pragma unroll
    for (int t = 0; t < 9; t++) {
      const int di = t / 3 - 1, dj = t % 3 - 1;
      // stage B for this tap (safe: previous MFMA drained by loop-tail barrier)
#pragma unroll
      for (int it = 0; it < 2; it++) {
        int idx = it * 256 + tid;
        int o = idx >> 2, co = (idx & 3) * 8;
        uint4 v = *(const uint4*)&wbf[((size_t)t * (HSC * DIMC)) + (size_t)(n0g + o) * DIMC + c0 + co];
        *(uint4*)&Bs[o * 40 + co] = v;
      }
      __syncthreads();

      bf16x8 a[4], bfr[4];
#pragma unroll
      for (int mi = 0; mi < 4; mi++) {
        const int col = mi * 16 + lo;
        a[mi] = *(const bf16x8*)&Xs[((wm + di + 1) * 66 + col + dj + 1) * 40 + hi * 8];
      }
#pragma unroll
      for (int ni = 0; ni < 4; ni++)
        bfr[ni] = *(const bf16x8*)&Bs[(wn * 64 + ni * 16 + lo) * 40 + hi * 8];
#pragma unroll
      for (int mi = 0; mi < 4; mi++)
#pragma unroll
        for (int ni = 0; ni < 4; ni++)
          acc[mi][ni] = __builtin_amdgcn_mfma_f32_16x16x32_bf16(a[mi], bfr[ni], acc[mi][ni], 0, 0, 0);
      __syncthreads();
    }
  }

  const int h = h0 + wm;
#pragma unroll
  for (int ni = 0; ni < 4; ni++) {
    const int o = n0g + wn * 64 + ni * 16 + lo;
    const float bia = bias[o];
    float T = 0.f;
#pragma unroll
    for (int mi = 0; mi < 4; mi++)
#pragma unroll
      for (int r = 0; r < 4; r++)
        T += fmaxf(acc[mi][ni][r] + bia, 0.f);
    T += __shfl_xor(T, 16);
    T += __shfl_xor(T, 32);
    float* ag = &agg[((size_t)bb * HSC + o) * 9];
    if (hi == 0) {
      atomicAdd(ag + 0, T);
      if (h == 0)  atomicAdd(ag + 1, T);
      if (h == 63) atomicAdd(ag + 2, T);
      float c0v = fmaxf(acc[0][ni][0] + bia, 0.f);
      atomicAdd(ag + 3, c0v);
      if (h == 0)  atomicAdd(ag + 5, c0v);
      if (h == 63) atomicAdd(ag + 7, c0v);
    }
    if (hi == 3) {
      float cwv = fmaxf(acc[3][ni][3] + bia, 0.f);
      atomicAdd(ag + 4, cwv);
      if (h == 0)  atomicAdd(ag + 6, cwv);
      if (h == 63) atomicAdd(ag + 8, cwv);
    }
  }
}

// ---------------- aggregates -> 9 tap sums ----------------
__global__ void tap_compute(const float* __restrict__ agg, float* __restrict__ tap)
{
  int b = blockIdx.x; int c = threadIdx.x;
  const float* a = &agg[((size_t)b * HSC + c) * 9];
  float T = a[0], R0 = a[1], RH = a[2], C0 = a[3], CW = a[4];
  float s00 = a[5], s0W = a[6], sH0 = a[7], sHW = a[8];
  float* tp = &tap[((size_t)b * HSC + c) * 9];
#pragma unroll
  for (int i = 0; i < 3; i++)
#pragma unroll
    for (int j = 0; j < 3; j++) {
      int di = i - 1, dj = j - 1;
      float v = T;
      if (di == -1) v -= RH; else if (di == 1) v -= R0;
      if (dj == -1) v -= CW; else if (dj == 1) v -= C0;
      if (di == -1 && dj == -1) v += sHW;
      if (di == -1 && dj ==  1) v += sH0;
      if (di ==  1 && dj == -1) v += s0W;
      if (di ==  1 && dj ==  1) v += s00;
      tp[i * 3 + j] = v * (1.f / 4096.f);
    }
}

// ---------------- routing fc2 + softmax over NF ----------------
__global__ __launch_bounds__(256) void route_softmax(
    const float* __restrict__ meansum, const float* __restrict__ W,
    const float* __restrict__ bias, float* __restrict__ route)
{
  __shared__ float mv[HRC];
  int b = blockIdx.y;
  int m = blockIdx.x * 256 + threadIdx.x;
  mv[threadIdx.x] = meansum[b * HRC + threadIdx.x] * (1.f / 4096.f);
  __syncthreads();
  float l[4];
#pragma unroll
  for (int f = 0; f < 4; f++) {
    int o = f * MEDC + m;
    float accv = bias[o];
    const float* wr = &W[(size_t)o * HRC];
    for (int c = 0; c < HRC; c++) accv += wr[c] * mv[c];
    l[f] = accv;
  }
  float mx = fmaxf(fmaxf(l[0], l[1]), fmaxf(l[2], l[3]));
  float e[4], s = 0.f;
#pragma unroll
  for (int f = 0; f < 4; f++) { e[f] = expf(l[f] - mx); s += e[f]; }
  float inv = 1.f / s;
#pragma unroll
  for (int f = 0; f < 4; f++) route[((size_t)b * 4 + f) * MEDC + m] = e[f] * inv;
}

// ---------------- spatial routing fc2 (9-tap) + softmax ----------------
__global__ __launch_bounds__(256) void sproute_softmax(
    const float* __restrict__ tap, const float* __restrict__ W,
    const float* __restrict__ bias, float* __restrict__ sroute)
{
  __shared__ float tv[HSC * 9];
  int b = blockIdx.y;
  int m = blockIdx.x * 256 + threadIdx.x;
#pragma unroll
  for (int i = 0; i < 9; i++) {
    int idx = i * 256 + threadIdx.x;
    tv[idx] = tap[(size_t)b * HSC * 9 + idx];
  }
  __syncthreads();
  float l[4];
#pragma unroll
  for (int f = 0; f < 4; f++) {
    int o = f * MEDC + m;
    float accv = bias[o];
    const float* wr = &W[(size_t)o * HSC * 9];
    for (int ct = 0; ct < HSC * 9; ct++) accv += wr[ct] * tv[ct];
    l[f] = accv;
  }
  float mx = fmaxf(fmaxf(l[0], l[1]), fmaxf(l[2], l[3]));
  float e[4], s = 0.f;
#pragma unroll
  for (int f = 0; f < 4; f++) { e[f] = expf(l[f] - mx); s += e[f]; }
  float inv = 1.f / s;
#pragma unroll
  for (int f = 0; f < 4; f++) sroute[((size_t)b * 4 + f) * MEDC + m] = e[f] * inv;
}

// ---------------- compile-time twiddle tables: cos/sin(2*pi*a/64) ----------------
constexpr float TWC64[64] = {
  1.00000000f, 0.99518473f, 0.98078528f, 0.95694034f, 0.92387953f, 0.88192126f, 0.83146961f, 0.77301045f,
  0.70710678f, 0.63439328f, 0.55557023f, 0.47139674f, 0.38268343f, 0.29028468f, 0.19509032f, 0.09801714f,
  0.00000000f,-0.09801714f,-0.19509032f,-0.29028468f,-0.38268343f,-0.47139674f,-0.55557023f,-0.63439328f,
 -0.70710678f,-0.77301045f,-0.83146961f,-0.88192126f,-0.92387953f,-0.95694034f,-0.98078528f,-0.99518473f,
 -1.00000000f,-0.99518473f,-0.98078528f,-0.95694034f,-0.92387953f,-0.88192126f,-0.83146961f,-0.77301045f,
 -0.70710678f,-0.63439328f,-0.55557023f,-0.47139674f,-0.38268343f,-0.29028468f,-0.19509032f,-0.09801714f,
 -0.00000000f, 0.09801714f, 0.19509032f, 0.29028468f, 0.38268343f, 0.47139674f, 0.55557023f, 0.63439328f,
  0.70710678f, 0.77301045f, 0.83146961f, 0.88192126f, 0.92387953f, 0.95694034f, 0.98078528f, 0.99518473f
};
constexpr float TWS64[64] = {
  0.00000000f, 0.09801714f, 0.19509032f, 0.29028468f, 0.38268343f, 0.47139674f, 0.55557023f, 0.63439328f,
  0.70710678f, 0.77301045f, 0.83146961f, 0.88192126f, 0.92387953f, 0.95694034f, 0.98078528f, 0.99518473f,
  1.00000000f, 0.99518473f, 0.98078528f, 0.95694034f, 0.92387953f, 0.88192126f, 0.83146961f, 0.77301045f,
  0.70710678f, 0.63439328f, 0.55557023f, 0.47139674f, 0.38268343f, 0.29028468f, 0.19509032f, 0.09801714f,
  0.00000000f,-0.09801714f,-0.19509032f,-0.29028468f,-0.38268343f,-0.47139674f,-0.55557023f,-0.63439328f,
 -0.70710678f,-0.77301045f,-0.83146961f,-0.88192126f,-0.92387953f,-0.95694034f,-0.98078528f,-0.99518473f,
 -1.00000000f,-0.99518473f,-0.98078528f,-0.95694034f,-0.92387953f,-0.88192126f,-0.83146961f,-0.77301045f,
 -0.70710678f,-0.63439328f,-0.55557023f,-0.47139674f,-0.38268343f,-0.29028468f,-0.19509032f,-0.09801714f
};

// ---------------- radix-8 DFT helpers (register-resident) ----------------
template<int SGN>
__device__ __forceinline__ void dft8(const float* xr, const float* xi, float* Xr, float* Xi) {
  const float S = (float)SGN;
  const float r = 0.70710678118654752440f;
  float t0r = xr[0] + xr[4], t0i = xi[0] + xi[4];
  float t1r = xr[0] - xr[4], t1i = xi[0] - xi[4];
  float t2r = xr[2] + xr[6], t2i = xi[2] + xi[6];
  float t3r = xr[2] - xr[6], t3i = xi[2] - xi[6];
  float E0r = t0r + t2r, E0i = t0i + t2i;
  float E2r = t0r - t2r, E2i = t0i - t2i;
  float E1r = t1r - S * t3i, E1i = t1i + S * t3r;
  float E3r = t1r + S * t3i, E3i = t1i - S * t3r;
  float u0r = xr[1] + xr[5], u0i = xi[1] + xi[5];
  float u1r = xr[1] - xr[5], u1i = xi[1] - xi[5];
  float u2r = xr[3] + xr[7], u2i = xi[3] + xi[7];
  float u3r = xr[3] - xr[7], u3i = xi[3] - xi[7];
  float O0r = u0r + u2r, O0i = u0i + u2i;
  float O2r = u0r - u2r, O2i = u0i - u2i;
  float O1r = u1r - S * u3i, O1i = u1i + S * u3r;
  float O3r = u1r + S * u3i, O3i = u1i - S * u3r;
  float p1r = r * (O1r - S * O1i), p1i = r * (S * O1r + O1i);
  float p2r = -S * O2i,            p2i = S * O2r;
  float p3r = -r * (O3r + S * O3i), p3i = r * (S * O3r - O3i);
  Xr[0] = E0r + O0r; Xi[0] = E0i + O0i;
  Xr[4] = E0r - O0r; Xi[4] = E0i - O0i;
  Xr[1] = E1r + p1r; Xi[1] = E1i + p1i;
  Xr[5] = E1r - p1r; Xi[5] = E1i - p1i;
  Xr[2] = E2r + p2r; Xi[2] = E2i + p2i;
  Xr[6] = E2r - p2r; Xi[6] = E2i - p2i;
  Xr[3] = E3r + p3r; Xi[3] = E3i + p3i;
  Xr[7] = E3r - p3r; Xi[7] = E3i - p3i;
}

template<int SGN>
__device__ __forceinline__ void dft8_strided(float* xr, float* xi, const int base, const int stride) {
  float ar[8], ai[8], Br[8], Bi[8];
#pragma unroll
  for (int j = 0; j < 8; j++) { ar[j] = xr[base + j * stride]; ai[j] = xi[base + j * stride]; }
  dft8<SGN>(ar, ai, Br, Bi);
#pragma unroll
  for (int j = 0; j < 8; j++) { xr[base + j * stride] = Br[j]; xi[base + j * stride] = Bi[j]; }
}

template<int SGN>
__device__ __forceinline__ void twiddle_all(float* xr, float* xi) {
#pragma unroll
  for (int s = 0; s < 64; s++) {
    const int a = (s >> 3) * (s & 7);
    if (a) {
      const float c = TWC64[a];
      const float si = (float)SGN * TWS64[a];
      float rr = xr[s] * c - xi[s] * si;
      xi[s] = xr[s] * si + xi[s] * c;
      xr[s] = rr;
    }
  }
}

// 64-pt DFT, natural-order input -> digit-reversed output: slot 8*k1+k2 holds X[k1+8*k2].
template<int SGN>
__device__ __forceinline__ void fft64_n2r(float* xr, float* xi) {
#pragma unroll
  for (int g = 0; g < 8; g++) dft8_strided<SGN>(xr, xi, g, 8);
  twiddle_all<SGN>(xr, xi);
#pragma unroll
  for (int g = 0; g < 8; g++) dft8_strided<SGN>(xr, xi, 8 * g, 1);
}

// 64-pt DFT, digit-reversed input -> natural-order output.
template<int SGN>
__device__ __forceinline__ void fft64_r2n(float* xr, float* xi) {
#pragma unroll
  for (int g = 0; g < 8; g++) dft8_strided<SGN>(xr, xi, 8 * g, 1);
  twiddle_all<SGN>(xr, xi);
#pragma unroll
  for (int g = 0; g < 8; g++) dft8_strided<SGN>(xr, xi, g, 8);
}

// ---------------- FFT filter: 2 waves per block, 1 image per wave ----------------
__global__ __launch_bounds__(128, 1) void fft_filter(
    float* __restrict__ xp, const float* __restrict__ route,
    const float* __restrict__ sroute, const float* __restrict__ cw,
    const float* __restrict__ spw)
{
  __shared__ float Sbuf[2 * 64 * 66];   // 33792 B
  const int wave = threadIdx.x >> 6;
  const int lane = threadIdx.x & 63;
  float* S = &Sbuf[wave * (64 * 66)];
  float2* Fs = (float2*)S;
  const int blk = blockIdx.x * 2 + wave;
  const int b = blk >> 10;
  const int m = blk & 1023;
  float* img = xp + (size_t)blk * HW;

  float r4[4], s4[4];
#pragma unroll
  for (int f = 0; f < 4; f++) {
    r4[f] = route[((size_t)b * 4 + f) * MEDC + m] * (1.f / 4096.f);  // fold ortho norm
    s4[f] = sroute[((size_t)b * 4 + f) * MEDC + m];
  }

  // ==== stage in: coalesced global -> S (as X, stride 65) ====
#pragma unroll
  for (int t = 0; t < 16; t++) {
    const int idx = t * 64 + lane;
    float4 v = *(const float4*)&img[idx * 4];
    const int row = idx >> 4;
    const int col = (idx & 15) * 4;
    S[row * 65 + col + 0] = v.x;
    S[row * 65 + col + 1] = v.y;
    S[row * 65 + col + 2] = v.z;
    S[row * 65 + col + 3] = v.w;
  }
  __syncthreads();

  float xr[64], xi[64];

  // ==== pass 1: row forward rfft ====
#pragma unroll
  for (int w = 0; w < 64; w++) { xr[w] = S[lane * 65 + w]; xi[w] = 0.f; }
  __syncthreads();
  fft64_n2r<-1>(xr, xi);
#pragma unroll
  for (int k1 = 0; k1 < 8; k1++)
#pragma unroll
    for (int k2 = 0; k2 < 5; k2++) {
      const int k = k1 + 8 * k2;
      if (k <= 32)
        Fs[lane * 33 + k] = make_float2(xr[8 * k1 + k2], xi[8 * k1 + k2]);
    }
  __syncthreads();

  // ==== col pass: fwd fft + weight + inv fft, in registers (lane k < 33) ====
  if (lane < 33) {
#pragma unroll
    for (int h = 0; h < 64; h++) {
      float2 v = Fs[h * 33 + lane];
      xr[h] = v.x; xi[h] = v.y;
    }
    fft64_n2r<-1>(xr, xi);
#pragma unroll
    for (int s = 0; s < 64; s++) {
      const int kh = (s >> 3) + 8 * (s & 7);
      const float* cwp = &cw[(size_t)(kh * 33 + lane) * 8];
      float4 c0 = *(const float4*)cwp;
      float4 c1 = *(const float4*)(cwp + 4);
      float wre = r4[0] * c0.x + r4[1] * c0.z + r4[2] * c1.x + r4[3] * c1.z;
      float wim = r4[0] * c0.y + r4[1] * c0.w + r4[2] * c1.y + r4[3] * c1.w;
      float rr = xr[s] * wre - xi[s] * wim;
      xi[s] = xr[s] * wim + xi[s] * wre;
      xr[s] = rr;
    }
    fft64_r2n<1>(xr, xi);
#pragma unroll
    for (int h = 0; h < 64; h++)
      Fs[h * 33 + lane] = make_float2(xr[h], xi[h]);
  }
  __syncthreads();

  // ==== pass 4a: read spectrum row into registers (Hermitian pack) ====
#pragma unroll
  for (int k = 0; k < 33; k++) {
    float2 v = Fs[lane * 33 + k];
    if (k == 0 || k == 32) { xr[k] = v.x; xi[k] = 0.f; }
    else                   { xr[k] = 2.f * v.x; xi[k] = 2.f * v.y; }
  }
#pragma unroll
  for (int k = 33; k < 64; k++) { xr[k] = 0.f; xi[k] = 0.f; }
  __syncthreads();

  fft64_n2r<1>(xr, xi);

  // ==== re-stage img -> S (as X) for the gating term ====
#pragma unroll
  for (int t = 0; t < 16; t++) {
    const int idx = t * 64 + lane;
    float4 v = *(const float4*)&img[idx * 4];
    const int row = idx >> 4;
    const int col = (idx & 15) * 4;
    S[row * 65 + col + 0] = v.x;
    S[row * 65 + col + 1] = v.y;
    S[row * 65 + col + 2] = v.z;
    S[row * 65 + col + 3] = v.w;
  }
  __syncthreads();

  // ==== pass 4b: gating + add, write own row back into S ====
#pragma unroll
  for (int w = 0; w < 64; w++) {
    const int s = 8 * (w & 7) + (w >> 3);
    float4 sp = *(const float4*)&spw[(size_t)(lane * 64 + w) * 4];
    float sw = s4[0] * sp.x + s4[1] * sp.y + s4[2] * sp.z + s4[3] * sp.w;
    S[lane * 65 + w] = S[lane * 65 + w] * sw + xr[s];
  }
  __syncthreads();

  // ==== stage out: S -> coalesced global ====
#pragma unroll
  for (int t = 0; t < 16; t++) {
    const int idx = t * 64 + lane;
    const int row = idx >> 4;
    const int col = (idx & 15) * 4;
    float4 o;
    o.x = S[row * 65 + col + 0];
    o.y = S[row * 65 + col + 1];
    o.z = S[row * 65 + col + 2];
    o.w = S[row * 65 + col + 3];
    *(float4*)&img[idx * 4] = o;
  }
}

extern "C" void kernel_launch(void* const* d_in, const int* in_sizes, int n_in,
                              void* d_out, int out_size, void* d_ws, size_t ws_size,
                              hipStream_t stream) {
  const float* x          = (const float*)d_in[0];
  const float* w_pw1      = (const float*)d_in[1];
  const float* w_pw2      = (const float*)d_in[2];
  const float* star_scale = (const float*)d_in[3];
  const float* star_bias  = (const float*)d_in[4];
  const float* rw1w = (const float*)d_in[5];
  const float* rw1b = (const float*)d_in[6];
  const float* rwcw = (const float*)d_in[7];
  const float* rwcb = (const float*)d_in[8];
  const float* rw2w = (const float*)d_in[9];
  const float* rw2b = (const float*)d_in[10];
  const float* sp1w = (const float*)d_in[11];
  const float* sp1b = (const float*)d_in[12];
  const float* sp2w = (const float*)d_in[13];
  const float* sp2b = (const float*)d_in[14];
  const float* cw   = (const float*)d_in[15];
  const float* spw  = (const float*)d_in[16];

  if (ws_size < WS_END * sizeof(float)) return;

  float* ws = (float*)d_ws;
  float* xp = ws + XP_OFF;
  unsigned short* r1    = (unsigned short*)(ws + R1_OFF);
  unsigned short* xT    = (unsigned short*)(ws + XT_OFF);
  unsigned short* wconv = (unsigned short*)(ws + WCONV_OFF);
  unsigned short* wr1   = (unsigned short*)(ws + WR1_OFF);
  unsigned short* wrc   = (unsigned short*)(ws + WRC_OFF);
  unsigned short* wb1   = (unsigned short*)(ws + WB1_OFF);
  unsigned short* wb2   = (unsigned short*)(ws + WB2_OFF);
  float* meansum = ws + MEAN_OFF;
  float* agg     = ws + AGG_OFF;
  float* tap     = ws + TAP_OFF;
  float* route   = ws + ROUTE_OFF;
  float* sr      = ws + SR_OFF;
  float* out = (float*)d_out;

  hipMemsetAsync(meansum, 0, (4096 + 36864) * sizeof(float), stream);

  // bf16 prep
  xpose_bf16<<<dim3(128, 16, 16), 256, 0, stream>>>(x, xT);
  wconv_bf16<<<512, 256, 0, stream>>>(sp1w, wconv);
  cvt_bf16<<<2048, 256, 0, stream>>>(w_pw1, wb1, MEDC * DIMC);
  cvt_bf16<<<2048, 256, 0, stream>>>(w_pw2, wb2, DIMC * MEDC);
  cvt_bf16<<<512, 256, 0, stream>>>(rw1w, wr1, HRC * DIMC);
  cvt_bf16<<<256, 256, 0, stream>>>(rwcw, wrc, HRC * HRC);

  // routing branch (bf16 MFMA)
  gemm_bf16<1, 0><<<dim3(32, 2, 16), 256, 0, stream>>>(
      xT, wr1, rw1b, nullptr, r1, nullptr, nullptr, nullptr, DIMC, HRC);
  gemm_bf16<3, 0><<<dim3(32, 2, 16), 256, 0, stream>>>(
      r1, wrc, rwcb, nullptr, nullptr, meansum, nullptr, nullptr, HRC, HRC);
  route_softmax<<<dim3(4, 16), 256, 0, stream>>>(meansum, rw2w, rw2b, route);

  // spatial routing branch (bf16 MFMA conv, halo-LDS)
  conv3_mfma<<<dim3(32, 2, 16), 256, 0, stream>>>(xT, wconv, sp1b, agg);
  tap_compute<<<16, 256, 0, stream>>>(agg, tap);
  sproute_softmax<<<dim3(4, 16), 256, 0, stream>>>(tap, sp2w, sp2b, sr);

  // main path (bf16 MFMA) — pw1 reads f32 x (ASRC1): xT aliases the xp region (race if ASRC0)
  gemm_bf16<2, 1><<<dim3(32, 8, 16), 256, 0, stream>>>(
      x, wb1, nullptr, xp, nullptr, nullptr, star_scale, star_bias, DIMC, MEDC);
  fft_filter<<<8192, 128, 0, stream>>>(xp, route, sr, cw, spw);
  gemm_bf16<0, 1><<<dim3(32, 4, 16), 256, 0, stream>>>(
      xp, wb2, nullptr, out, nullptr, nullptr, nullptr, nullptr, MEDC, DIMC);
}

// Round 15
// 1641.262 us; speedup vs baseline: 1.0823x; 1.0823x over previous
//
#include <hip/hip_runtime.h>

#define HW    4096
#define DIMC  512
#define MEDC  1024
#define HRC   256
#define HSC   256
#define NBATCH 16

typedef __attribute__((ext_vector_type(8))) short bf16x8;
typedef __attribute__((ext_vector_type(4))) float f32x4;

// ---------------- workspace layout (floats) ----------------
static const size_t R1_OFF    = 0;
static const size_t XT_OFF    = 8388608;
static const size_t WCONV_OFF = 25165824;
static const size_t WR1_OFF   = 25755648;
static const size_t WRC_OFF   = 25821184;
static const size_t XP_OFF    = 0;
static const size_t WB1_OFF   = 67108864;
static const size_t WB2_OFF   = 67371008;
static const size_t MEAN_OFF  = 67633152;
static const size_t AGG_OFF   = MEAN_OFF + 4096;
static const size_t TAP_OFF   = AGG_OFF + 36864;
static const size_t ROUTE_OFF = TAP_OFF + 36864;
static const size_t SR_OFF    = ROUTE_OFF + 65536;
static const size_t WS_END    = SR_OFF + 65536;

__device__ __forceinline__ unsigned short f2bf(float f) {
  unsigned u = __float_as_uint(f);
  unsigned r = (u + 0x7fffu + ((u >> 16) & 1u)) >> 16;
  return (unsigned short)r;
}

// ---------------- generic f32 -> bf16 elementwise ----------------
__global__ __launch_bounds__(256) void cvt_bf16(
    const float* __restrict__ src, unsigned short* __restrict__ dst, int n)
{
  int i = blockIdx.x * 256 + threadIdx.x;
  if (i < n) dst[i] = f2bf(src[i]);
}

// ---------------- x [b][c][4096] f32 -> xT [b][pix][512] bf16 ----------------
__global__ __launch_bounds__(256) void xpose_bf16(
    const float* __restrict__ x, unsigned short* __restrict__ xT)
{
  __shared__ unsigned short T[32][33];
  const int tid = threadIdx.x;
  const int p0 = blockIdx.x * 32, c0 = blockIdx.y * 32, bb = blockIdx.z;
#pragma unroll
  for (int i = 0; i < 4; i++) {
    int idx = i * 256 + tid;
    int c_l = idx >> 5, p_l = idx & 31;
    T[c_l][p_l] = f2bf(x[((size_t)(bb * DIMC + c0 + c_l)) * HW + p0 + p_l]);
  }
  __syncthreads();
#pragma unroll
  for (int i = 0; i < 4; i++) {
    int idx = i * 256 + tid;
    int p_l = idx >> 5, c_l = idx & 31;
    xT[((size_t)bb * HW + p0 + p_l) * DIMC + c0 + c_l] = T[c_l][p_l];
  }
}

// ---------------- sp1w [o][c][9] f32 -> wconv [t][o][c] bf16 ----------------
__global__ __launch_bounds__(256) void wconv_bf16(
    const float* __restrict__ w, unsigned short* __restrict__ wbf)
{
  int idx = blockIdx.x * 256 + threadIdx.x;
  if (idx < HSC * DIMC) {
#pragma unroll
    for (int t = 0; t < 9; t++)
      wbf[(size_t)t * (HSC * DIMC) + idx] = f2bf(w[(size_t)idx * 9 + t]);
  }
}

// ---------------- bf16 MFMA GEMM, 128 pix x 128 n tile, 4 waves ----------------
template<int EPI, int ASRC>
__global__ __launch_bounds__(256) void gemm_bf16(
    const void* __restrict__ Aptr, const unsigned short* __restrict__ Wb,
    const float* __restrict__ bias, float* __restrict__ Cf,
    unsigned short* __restrict__ Cb, float* __restrict__ meansum,
    const float* __restrict__ star_scale, const float* __restrict__ star_bias,
    int K, int Ntot)
{
  __shared__ __align__(16) unsigned short As[128 * 40];
  __shared__ __align__(16) unsigned short Bs[128 * 40];
  const int tid = threadIdx.x;
  const int pix0 = blockIdx.x * 128;
  const int n0g = blockIdx.y * 128;
  const int bb = blockIdx.z;
  const int wid = tid >> 6, lane = tid & 63;
  const int lo = lane & 15, hi = lane >> 4;
  const int wm = wid >> 1, wn = wid & 1;

  f32x4 acc[4][4];
#pragma unroll
  for (int mi = 0; mi < 4; mi++)
#pragma unroll
    for (int ni = 0; ni < 4; ni++) acc[mi][ni] = (f32x4){0.f, 0.f, 0.f, 0.f};

  const int nsteps = K >> 5;
  for (int s = 0; s < nsteps; s++) {
    const int c0 = s * 32;
    if (ASRC == 0) {
      const unsigned short* AT = (const unsigned short*)Aptr;
#pragma unroll
      for (int it = 0; it < 2; it++) {
        int idx = it * 256 + tid;
        int p = idx >> 2, co = (idx & 3) * 8;
        uint4 v = *(const uint4*)&AT[((size_t)bb * HW + pix0 + p) * K + c0 + co];
        *(uint4*)&As[p * 40 + co] = v;
      }
    } else {
      const float* Af = (const float*)Aptr;
#pragma unroll
      for (int it = 0; it < 16; it++) {
        int idx = it * 256 + tid;
        int k_l = idx >> 7, p_l = idx & 127;
        float v = Af[((size_t)bb * K + c0 + k_l) * HW + pix0 + p_l];
        As[p_l * 40 + k_l] = f2bf(v);
      }
    }
#pragma unroll
    for (int it = 0; it < 2; it++) {
      int idx = it * 256 + tid;
      int o = idx >> 2, co = (idx & 3) * 8;
      uint4 v = *(const uint4*)&Wb[(size_t)(n0g + o) * K + c0 + co];
      *(uint4*)&Bs[o * 40 + co] = v;
    }
    __syncthreads();

    bf16x8 a[4], bq[4];
#pragma unroll
    for (int mi = 0; mi < 4; mi++)
      a[mi] = *(const bf16x8*)&As[(wm * 64 + mi * 16 + lo) * 40 + hi * 8];
#pragma unroll
    for (int ni = 0; ni < 4; ni++)
      bq[ni] = *(const bf16x8*)&Bs[(wn * 64 + ni * 16 + lo) * 40 + hi * 8];
#pragma unroll
    for (int mi = 0; mi < 4; mi++)
#pragma unroll
      for (int ni = 0; ni < 4; ni++)
        acc[mi][ni] = __builtin_amdgcn_mfma_f32_16x16x32_bf16(a[mi], bq[ni], acc[mi][ni], 0, 0, 0);
    __syncthreads();
  }

  if (EPI == 3) {
#pragma unroll
    for (int ni = 0; ni < 4; ni++) {
      const int n = n0g + wn * 64 + ni * 16 + lo;
      const float bia = bias[n];
      float T = 0.f;
#pragma unroll
      for (int mi = 0; mi < 4; mi++)
#pragma unroll
        for (int r = 0; r < 4; r++)
          T += fmaxf(acc[mi][ni][r] + bia, 0.f);
      T += __shfl_xor(T, 16);
      T += __shfl_xor(T, 32);
      if (hi == 0) atomicAdd(&meansum[bb * Ntot + n], T);
    }
    return;
  }

  if (EPI == 1) {
#pragma unroll
    for (int ni = 0; ni < 4; ni++) {
      const int n = n0g + wn * 64 + ni * 16 + lo;
      const float bia = bias[n];
#pragma unroll
      for (int mi = 0; mi < 4; mi++)
#pragma unroll
        for (int r = 0; r < 4; r++) {
          const int pix = pix0 + wm * 64 + mi * 16 + hi * 4 + r;
          Cb[((size_t)bb * HW + pix) * Ntot + n] = f2bf(fmaxf(acc[mi][ni][r] + bia, 0.f));
        }
    }
    return;
  }

  float ss = 1.f, sb = 0.f;
  if (EPI == 2) { ss = star_scale[0]; sb = star_bias[0]; }
#pragma unroll
  for (int ni = 0; ni < 4; ni++) {
    const int n = n0g + wn * 64 + ni * 16 + lo;
#pragma unroll
    for (int mi = 0; mi < 4; mi++) {
      const int pixb = pix0 + wm * 64 + mi * 16 + hi * 4;
      float4 v;
      float* vv = (float*)&v;
#pragma unroll
      for (int r = 0; r < 4; r++) {
        float t = acc[mi][ni][r];
        if (EPI == 2) { t = fmaxf(t, 0.f); t = ss * t * t + sb; }
        vv[r] = t;
      }
      *(float4*)&Cf[((size_t)bb * Ntot + n) * HW + pixb] = v;
    }
  }
}

// ---------------- sp_fc1 3x3 conv (bf16 MFMA implicit GEMM) + relu + aggregates ----------------
__global__ __launch_bounds__(256) void conv3_mfma(
    const unsigned short* __restrict__ xT, const unsigned short* __restrict__ wbf,
    const float* __restrict__ bias, float* __restrict__ agg)
{
  __shared__ __align__(16) unsigned short As[128 * 40];
  __shared__ __align__(16) unsigned short Bs[128 * 40];
  const int tid = threadIdx.x;
  const int bx = blockIdx.x;
  const int n0g = blockIdx.y * 128;
  const int bb = blockIdx.z;
  const int h0 = bx * 2;
  const int wid = tid >> 6;
  const int lane = tid & 63;
  const int lo = lane & 15, hi = lane >> 4;
  const int wm = wid >> 1;
  const int wn = wid & 1;

  f32x4 acc[4][4];
#pragma unroll
  for (int mi = 0; mi < 4; mi++)
#pragma unroll
    for (int ni = 0; ni < 4; ni++) acc[mi][ni] = (f32x4){0.f, 0.f, 0.f, 0.f};

  for (int s = 0; s < 144; s++) {
    const int t = s >> 4;
    const int c0 = (s & 15) * 32;
    const int di = t / 3 - 1, dj = t % 3 - 1;
#pragma unroll
    for (int it = 0; it < 2; it++) {
      int idx = it * 256 + tid;
      int pix = idx >> 2, co = (idx & 3) * 8;
      int h = h0 + (pix >> 6) + di;
      int col = (pix & 63) + dj;
      uint4 v = make_uint4(0u, 0u, 0u, 0u);
      if (h >= 0 && h < 64 && col >= 0 && col < 64)
        v = *(const uint4*)&xT[((size_t)bb * HW + h * 64 + col) * DIMC + c0 + co];
      *(uint4*)&As[pix * 40 + co] = v;
    }
#pragma unroll
    for (int it = 0; it < 2; it++) {
      int idx = it * 256 + tid;
      int o = idx >> 2, co = (idx & 3) * 8;
      uint4 v = *(const uint4*)&wbf[((size_t)t * (HSC * DIMC)) + (size_t)(n0g + o) * DIMC + c0 + co];
      *(uint4*)&Bs[o * 40 + co] = v;
    }
    __syncthreads();

    bf16x8 a[4], bfr[4];
#pragma unroll
    for (int mi = 0; mi < 4; mi++)
      a[mi] = *(const bf16x8*)&As[(wm * 64 + mi * 16 + lo) * 40 + hi * 8];
#pragma unroll
    for (int ni = 0; ni < 4; ni++)
      bfr[ni] = *(const bf16x8*)&Bs[(wn * 64 + ni * 16 + lo) * 40 + hi * 8];
#pragma unroll
    for (int mi = 0; mi < 4; mi++)
#pragma unroll
      for (int ni = 0; ni < 4; ni++)
        acc[mi][ni] = __builtin_amdgcn_mfma_f32_16x16x32_bf16(a[mi], bfr[ni], acc[mi][ni], 0, 0, 0);
    __syncthreads();
  }

  const int h = h0 + wm;
#pragma unroll
  for (int ni = 0; ni < 4; ni++) {
    const int o = n0g + wn * 64 + ni * 16 + lo;
    const float bia = bias[o];
    float T = 0.f;
#pragma unroll
    for (int mi = 0; mi < 4; mi++)
#pragma unroll
      for (int r = 0; r < 4; r++)
        T += fmaxf(acc[mi][ni][r] + bia, 0.f);
    T += __shfl_xor(T, 16);
    T += __shfl_xor(T, 32);
    float* ag = &agg[((size_t)bb * HSC + o) * 9];
    if (hi == 0) {
      atomicAdd(ag + 0, T);
      if (h == 0)  atomicAdd(ag + 1, T);
      if (h == 63) atomicAdd(ag + 2, T);
      float c0v = fmaxf(acc[0][ni][0] + bia, 0.f);
      atomicAdd(ag + 3, c0v);
      if (h == 0)  atomicAdd(ag + 5, c0v);
      if (h == 63) atomicAdd(ag + 7, c0v);
    }
    if (hi == 3) {
      float cwv = fmaxf(acc[3][ni][3] + bia, 0.f);
      atomicAdd(ag + 4, cwv);
      if (h == 0)  atomicAdd(ag + 6, cwv);
      if (h == 63) atomicAdd(ag + 8, cwv);
    }
  }
}

// ---------------- aggregates -> 9 tap sums ----------------
__global__ void tap_compute(const float* __restrict__ agg, float* __restrict__ tap)
{
  int b = blockIdx.x; int c = threadIdx.x;
  const float* a = &agg[((size_t)b * HSC + c) * 9];
  float T = a[0], R0 = a[1], RH = a[2], C0 = a[3], CW = a[4];
  float s00 = a[5], s0W = a[6], sH0 = a[7], sHW = a[8];
  float* tp = &tap[((size_t)b * HSC + c) * 9];
#pragma unroll
  for (int i = 0; i < 3; i++)
#pragma unroll
    for (int j = 0; j < 3; j++) {
      int di = i - 1, dj = j - 1;
      float v = T;
      if (di == -1) v -= RH; else if (di == 1) v -= R0;
      if (dj == -1) v -= CW; else if (dj == 1) v -= C0;
      if (di == -1 && dj == -1) v += sHW;
      if (di == -1 && dj ==  1) v += sH0;
      if (di ==  1 && dj == -1) v += s0W;
      if (di ==  1 && dj ==  1) v += s00;
      tp[i * 3 + j] = v * (1.f / 4096.f);
    }
}

// ---------------- routing fc2 + softmax over NF ----------------
__global__ __launch_bounds__(256) void route_softmax(
    const float* __restrict__ meansum, const float* __restrict__ W,
    const float* __restrict__ bias, float* __restrict__ route)
{
  __shared__ float mv[HRC];
  int b = blockIdx.y;
  int m = blockIdx.x * 256 + threadIdx.x;
  mv[threadIdx.x] = meansum[b * HRC + threadIdx.x] * (1.f / 4096.f);
  __syncthreads();
  float l[4];
#pragma unroll
  for (int f = 0; f < 4; f++) {
    int o = f * MEDC + m;
    float accv = bias[o];
    const float* wr = &W[(size_t)o * HRC];
    for (int c = 0; c < HRC; c++) accv += wr[c] * mv[c];
    l[f] = accv;
  }
  float mx = fmaxf(fmaxf(l[0], l[1]), fmaxf(l[2], l[3]));
  float e[4], s = 0.f;
#pragma unroll
  for (int f = 0; f < 4; f++) { e[f] = expf(l[f] - mx); s += e[f]; }
  float inv = 1.f / s;
#pragma unroll
  for (int f = 0; f < 4; f++) route[((size_t)b * 4 + f) * MEDC + m] = e[f] * inv;
}

// ---------------- spatial routing fc2 (9-tap) + softmax ----------------
__global__ __launch_bounds__(256) void sproute_softmax(
    const float* __restrict__ tap, const float* __restrict__ W,
    const float* __restrict__ bias, float* __restrict__ sroute)
{
  __shared__ float tv[HSC * 9];
  int b = blockIdx.y;
  int m = blockIdx.x * 256 + threadIdx.x;
#pragma unroll
  for (int i = 0; i < 9; i++) {
    int idx = i * 256 + threadIdx.x;
    tv[idx] = tap[(size_t)b * HSC * 9 + idx];
  }
  __syncthreads();
  float l[4];
#pragma unroll
  for (int f = 0; f < 4; f++) {
    int o = f * MEDC + m;
    float accv = bias[o];
    const float* wr = &W[(size_t)o * HSC * 9];
    for (int ct = 0; ct < HSC * 9; ct++) accv += wr[ct] * tv[ct];
    l[f] = accv;
  }
  float mx = fmaxf(fmaxf(l[0], l[1]), fmaxf(l[2], l[3]));
  float e[4], s = 0.f;
#pragma unroll
  for (int f = 0; f < 4; f++) { e[f] = expf(l[f] - mx); s += e[f]; }
  float inv = 1.f / s;
#pragma unroll
  for (int f = 0; f < 4; f++) sroute[((size_t)b * 4 + f) * MEDC + m] = e[f] * inv;
}

// ---------------- compile-time twiddle tables: cos/sin(2*pi*a/64) ----------------
constexpr float TWC64[64] = {
  1.00000000f, 0.99518473f, 0.98078528f, 0.95694034f, 0.92387953f, 0.88192126f, 0.83146961f, 0.77301045f,
  0.70710678f, 0.63439328f, 0.55557023f, 0.47139674f, 0.38268343f, 0.29028468f, 0.19509032f, 0.09801714f,
  0.00000000f,-0.09801714f,-0.19509032f,-0.29028468f,-0.38268343f,-0.47139674f,-0.55557023f,-0.63439328f,
 -0.70710678f,-0.77301045f,-0.83146961f,-0.88192126f,-0.92387953f,-0.95694034f,-0.98078528f,-0.99518473f,
 -1.00000000f,-0.99518473f,-0.98078528f,-0.95694034f,-0.92387953f,-0.88192126f,-0.83146961f,-0.77301045f,
 -0.70710678f,-0.63439328f,-0.55557023f,-0.47139674f,-0.38268343f,-0.29028468f,-0.19509032f,-0.09801714f,
 -0.00000000f, 0.09801714f, 0.19509032f, 0.29028468f, 0.38268343f, 0.47139674f, 0.55557023f, 0.63439328f,
  0.70710678f, 0.77301045f, 0.83146961f, 0.88192126f, 0.92387953f, 0.95694034f, 0.98078528f, 0.99518473f
};
constexpr float TWS64[64] = {
  0.00000000f, 0.09801714f, 0.19509032f, 0.29028468f, 0.38268343f, 0.47139674f, 0.55557023f, 0.63439328f,
  0.70710678f, 0.77301045f, 0.83146961f, 0.88192126f, 0.92387953f, 0.95694034f, 0.98078528f, 0.99518473f,
  1.00000000f, 0.99518473f, 0.98078528f, 0.95694034f, 0.92387953f, 0.88192126f, 0.83146961f, 0.77301045f,
  0.70710678f, 0.63439328f, 0.55557023f, 0.47139674f, 0.38268343f, 0.29028468f, 0.19509032f, 0.09801714f,
  0.00000000f,-0.09801714f,-0.19509032f,-0.29028468f,-0.38268343f,-0.47139674f,-0.55557023f,-0.63439328f,
 -0.70710678f,-0.77301045f,-0.83146961f,-0.88192126f,-0.92387953f,-0.95694034f,-0.98078528f,-0.99518473f,
 -1.00000000f,-0.99518473f,-0.98078528f,-0.95694034f,-0.92387953f,-0.88192126f,-0.83146961f,-0.77301045f,
 -0.70710678f,-0.63439328f,-0.55557023f,-0.47139674f,-0.38268343f,-0.29028468f,-0.19509032f,-0.09801714f
};

// ---------------- radix-8 DFT helpers (register-resident) ----------------
template<int SGN>
__device__ __forceinline__ void dft8(const float* xr, const float* xi, float* Xr, float* Xi) {
  const float S = (float)SGN;
  const float r = 0.70710678118654752440f;
  float t0r = xr[0] + xr[4], t0i = xi[0] + xi[4];
  float t1r = xr[0] - xr[4], t1i = xi[0] - xi[4];
  float t2r = xr[2] + xr[6], t2i = xi[2] + xi[6];
  float t3r = xr[2] - xr[6], t3i = xi[2] - xi[6];
  float E0r = t0r + t2r, E0i = t0i + t2i;
  float E2r = t0r - t2r, E2i = t0i - t2i;
  float E1r = t1r - S * t3i, E1i = t1i + S * t3r;
  float E3r = t1r + S * t3i, E3i = t1i - S * t3r;
  float u0r = xr[1] + xr[5], u0i = xi[1] + xi[5];
  float u1r = xr[1] - xr[5], u1i = xi[1] - xi[5];
  float u2r = xr[3] + xr[7], u2i = xi[3] + xi[7];
  float u3r = xr[3] - xr[7], u3i = xi[3] - xi[7];
  float O0r = u0r + u2r, O0i = u0i + u2i;
  float O2r = u0r - u2r, O2i = u0i - u2i;
  float O1r = u1r - S * u3i, O1i = u1i + S * u3r;
  float O3r = u1r + S * u3i, O3i = u1i - S * u3r;
  float p1r = r * (O1r - S * O1i), p1i = r * (S * O1r + O1i);
  float p2r = -S * O2i,            p2i = S * O2r;
  float p3r = -r * (O3r + S * O3i), p3i = r * (S * O3r - O3i);
  Xr[0] = E0r + O0r; Xi[0] = E0i + O0i;
  Xr[4] = E0r - O0r; Xi[4] = E0i - O0i;
  Xr[1] = E1r + p1r; Xi[1] = E1i + p1i;
  Xr[5] = E1r - p1r; Xi[5] = E1i - p1i;
  Xr[2] = E2r + p2r; Xi[2] = E2i + p2i;
  Xr[6] = E2r - p2r; Xi[6] = E2i - p2i;
  Xr[3] = E3r + p3r; Xi[3] = E3i + p3i;
  Xr[7] = E3r - p3r; Xi[7] = E3i - p3i;
}

template<int SGN>
__device__ __forceinline__ void dft8_strided(float* xr, float* xi, const int base, const int stride) {
  float ar[8], ai[8], Br[8], Bi[8];
#pragma unroll
  for (int j = 0; j < 8; j++) { ar[j] = xr[base + j * stride]; ai[j] = xi[base + j * stride]; }
  dft8<SGN>(ar, ai, Br, Bi);
#pragma unroll
  for (int j = 0; j < 8; j++) { xr[base + j * stride] = Br[j]; xi[base + j * stride] = Bi[j]; }
}

template<int SGN>
__device__ __forceinline__ void twiddle_all(float* xr, float* xi) {
#pragma unroll
  for (int s = 0; s < 64; s++) {
    const int a = (s >> 3) * (s & 7);
    if (a) {
      const float c = TWC64[a];
      const float si = (float)SGN * TWS64[a];
      float rr = xr[s] * c - xi[s] * si;
      xi[s] = xr[s] * si + xi[s] * c;
      xr[s] = rr;
    }
  }
}

// 64-pt DFT, natural-order input -> digit-reversed output: slot 8*k1+k2 holds X[k1+8*k2].
template<int SGN>
__device__ __forceinline__ void fft64_n2r(float* xr, float* xi) {
#pragma unroll
  for (int g = 0; g < 8; g++) dft8_strided<SGN>(xr, xi, g, 8);
  twiddle_all<SGN>(xr, xi);
#pragma unroll
  for (int g = 0; g < 8; g++) dft8_strided<SGN>(xr, xi, 8 * g, 1);
}

// 64-pt DFT, digit-reversed input -> natural-order output.
template<int SGN>
__device__ __forceinline__ void fft64_r2n(float* xr, float* xi) {
#pragma unroll
  for (int g = 0; g < 8; g++) dft8_strided<SGN>(xr, xi, 8 * g, 1);
  twiddle_all<SGN>(xr, xi);
#pragma unroll
  for (int g = 0; g < 8; g++) dft8_strided<SGN>(xr, xi, g, 8);
}

// ---------------- FFT filter: 2 waves per block, 1 image per wave ----------------
__global__ __launch_bounds__(128, 1) void fft_filter(
    float* __restrict__ xp, const float* __restrict__ route,
    const float* __restrict__ sroute, const float* __restrict__ cw,
    const float* __restrict__ spw)
{
  __shared__ float Sbuf[2 * 64 * 66];   // 33792 B
  const int wave = threadIdx.x >> 6;
  const int lane = threadIdx.x & 63;
  float* S = &Sbuf[wave * (64 * 66)];
  float2* Fs = (float2*)S;
  const int blk = blockIdx.x * 2 + wave;
  const int b = blk >> 10;
  const int m = blk & 1023;
  float* img = xp + (size_t)blk * HW;

  float r4[4], s4[4];
#pragma unroll
  for (int f = 0; f < 4; f++) {
    r4[f] = route[((size_t)b * 4 + f) * MEDC + m] * (1.f / 4096.f);  // fold ortho norm
    s4[f] = sroute[((size_t)b * 4 + f) * MEDC + m];
  }

  // ==== stage in: coalesced global -> S (as X, stride 65) ====
#pragma unroll
  for (int t = 0; t < 16; t++) {
    const int idx = t * 64 + lane;
    float4 v = *(const float4*)&img[idx * 4];
    const int row = idx >> 4;
    const int col = (idx & 15) * 4;
    S[row * 65 + col + 0] = v.x;
    S[row * 65 + col + 1] = v.y;
    S[row * 65 + col + 2] = v.z;
    S[row * 65 + col + 3] = v.w;
  }
  __syncthreads();

  float xr[64], xi[64];

  // ==== pass 1: row forward rfft ====
#pragma unroll
  for (int w = 0; w < 64; w++) { xr[w] = S[lane * 65 + w]; xi[w] = 0.f; }
  __syncthreads();
  fft64_n2r<-1>(xr, xi);
#pragma unroll
  for (int k1 = 0; k1 < 8; k1++)
#pragma unroll
    for (int k2 = 0; k2 < 5; k2++) {
      const int k = k1 + 8 * k2;
      if (k <= 32)
        Fs[lane * 33 + k] = make_float2(xr[8 * k1 + k2], xi[8 * k1 + k2]);
    }
  __syncthreads();

  // ==== col pass: fwd fft + weight + inv fft, in registers (lane k < 33) ====
  if (lane < 33) {
#pragma unroll
    for (int h = 0; h < 64; h++) {
      float2 v = Fs[h * 33 + lane];
      xr[h] = v.x; xi[h] = v.y;
    }
    fft64_n2r<-1>(xr, xi);
#pragma unroll
    for (int s = 0; s < 64; s++) {
      const int kh = (s >> 3) + 8 * (s & 7);
      const float* cwp = &cw[(size_t)(kh * 33 + lane) * 8];
      float4 c0 = *(const float4*)cwp;
      float4 c1 = *(const float4*)(cwp + 4);
      float wre = r4[0] * c0.x + r4[1] * c0.z + r4[2] * c1.x + r4[3] * c1.z;
      float wim = r4[0] * c0.y + r4[1] * c0.w + r4[2] * c1.y + r4[3] * c1.w;
      float rr = xr[s] * wre - xi[s] * wim;
      xi[s] = xr[s] * wim + xi[s] * wre;
      xr[s] = rr;
    }
    fft64_r2n<1>(xr, xi);
#pragma unroll
    for (int h = 0; h < 64; h++)
      Fs[h * 33 + lane] = make_float2(xr[h], xi[h]);
  }
  __syncthreads();

  // ==== pass 4a: read spectrum row into registers (Hermitian pack) ====
#pragma unroll
  for (int k = 0; k < 33; k++) {
    float2 v = Fs[lane * 33 + k];
    if (k == 0 || k == 32) { xr[k] = v.x; xi[k] = 0.f; }
    else                   { xr[k] = 2.f * v.x; xi[k] = 2.f * v.y; }
  }
#pragma unroll
  for (int k = 33; k < 64; k++) { xr[k] = 0.f; xi[k] = 0.f; }
  __syncthreads();

  fft64_n2r<1>(xr, xi);

  // ==== re-stage img -> S (as X) for the gating term ====
#pragma unroll
  for (int t = 0; t < 16; t++) {
    const int idx = t * 64 + lane;
    float4 v = *(const float4*)&img[idx * 4];
    const int row = idx >> 4;
    const int col = (idx & 15) * 4;
    S[row * 65 + col + 0] = v.x;
    S[row * 65 + col + 1] = v.y;
    S[row * 65 + col + 2] = v.z;
    S[row * 65 + col + 3] = v.w;
  }
  __syncthreads();

  // ==== pass 4b: gating + add, write own row back into S ====
#pragma unroll
  for (int w = 0; w < 64; w++) {
    const int s = 8 * (w & 7) + (w >> 3);
    float4 sp = *(const float4*)&spw[(size_t)(lane * 64 + w) * 4];
    float sw = s4[0] * sp.x + s4[1] * sp.y + s4[2] * sp.z + s4[3] * sp.w;
    S[lane * 65 + w] = S[lane * 65 + w] * sw + xr[s];
  }
  __syncthreads();

  // ==== stage out: S -> coalesced global ====
#pragma unroll
  for (int t = 0; t < 16; t++) {
    const int idx = t * 64 + lane;
    const int row = idx >> 4;
    const int col = (idx & 15) * 4;
    float4 o;
    o.x = S[row * 65 + col + 0];
    o.y = S[row * 65 + col + 1];
    o.z = S[row * 65 + col + 2];
    o.w = S[row * 65 + col + 3];
    *(float4*)&img[idx * 4] = o;
  }
}

extern "C" void kernel_launch(void* const* d_in, const int* in_sizes, int n_in,
                              void* d_out, int out_size, void* d_ws, size_t ws_size,
                              hipStream_t stream) {
  const float* x          = (const float*)d_in[0];
  const float* w_pw1      = (const float*)d_in[1];
  const float* w_pw2      = (const float*)d_in[2];
  const float* star_scale = (const float*)d_in[3];
  const float* star_bias  = (const float*)d_in[4];
  const float* rw1w = (const float*)d_in[5];
  const float* rw1b = (const float*)d_in[6];
  const float* rwcw = (const float*)d_in[7];
  const float* rwcb = (const float*)d_in[8];
  const float* rw2w = (const float*)d_in[9];
  const float* rw2b = (const float*)d_in[10];
  const float* sp1w = (const float*)d_in[11];
  const float* sp1b = (const float*)d_in[12];
  const float* sp2w = (const float*)d_in[13];
  const float* sp2b = (const float*)d_in[14];
  const float* cw   = (const float*)d_in[15];
  const float* spw  = (const float*)d_in[16];

  if (ws_size < WS_END * sizeof(float)) return;

  float* ws = (float*)d_ws;
  float* xp = ws + XP_OFF;
  unsigned short* r1    = (unsigned short*)(ws + R1_OFF);
  unsigned short* xT    = (unsigned short*)(ws + XT_OFF);
  unsigned short* wconv = (unsigned short*)(ws + WCONV_OFF);
  unsigned short* wr1   = (unsigned short*)(ws + WR1_OFF);
  unsigned short* wrc   = (unsigned short*)(ws + WRC_OFF);
  unsigned short* wb1   = (unsigned short*)(ws + WB1_OFF);
  unsigned short* wb2   = (unsigned short*)(ws + WB2_OFF);
  float* meansum = ws + MEAN_OFF;
  float* agg     = ws + AGG_OFF;
  float* tap     = ws + TAP_OFF;
  float* route   = ws + ROUTE_OFF;
  float* sr      = ws + SR_OFF;
  float* out = (float*)d_out;

  hipMemsetAsync(meansum, 0, (4096 + 36864) * sizeof(float), stream);

  // bf16 prep
  xpose_bf16<<<dim3(128, 16, 16), 256, 0, stream>>>(x, xT);
  wconv_bf16<<<512, 256, 0, stream>>>(sp1w, wconv);
  cvt_bf16<<<2048, 256, 0, stream>>>(w_pw1, wb1, MEDC * DIMC);
  cvt_bf16<<<2048, 256, 0, stream>>>(w_pw2, wb2, DIMC * MEDC);
  cvt_bf16<<<512, 256, 0, stream>>>(rw1w, wr1, HRC * DIMC);
  cvt_bf16<<<256, 256, 0, stream>>>(rwcw, wrc, HRC * HRC);

  // routing branch (bf16 MFMA)
  gemm_bf16<1, 0><<<dim3(32, 2, 16), 256, 0, stream>>>(
      xT, wr1, rw1b, nullptr, r1, nullptr, nullptr, nullptr, DIMC, HRC);
  gemm_bf16<3, 0><<<dim3(32, 2, 16), 256, 0, stream>>>(
      r1, wrc, rwcb, nullptr, nullptr, meansum, nullptr, nullptr, HRC, HRC);
  route_softmax<<<dim3(4, 16), 256, 0, stream>>>(meansum, rw2w, rw2b, route);

  // spatial routing branch (bf16 MFMA conv)
  conv3_mfma<<<dim3(32, 2, 16), 256, 0, stream>>>(xT, wconv, sp1b, agg);
  tap_compute<<<16, 256, 0, stream>>>(agg, tap);
  sproute_softmax<<<dim3(4, 16), 256, 0, stream>>>(tap, sp2w, sp2b, sr);

  // main path (bf16 MFMA) — pw1 reads f32 x (ASRC1): xT aliases the xp region (race if ASRC0)
  gemm_bf16<2, 1><<<dim3(32, 8, 16), 256, 0, stream>>>(
      x, wb1, nullptr, xp, nullptr, nullptr, star_scale, star_bias, DIMC, MEDC);
  fft_filter<<<8192, 128, 0, stream>>>(xp, route, sr, cw, spw);
  gemm_bf16<0, 1><<<dim3(32, 4, 16), 256, 0, stream>>>(
      xp, wb2, nullptr, out, nullptr, nullptr, nullptr, nullptr, MEDC, DIMC);
}

// Round 16
// 1565.046 us; speedup vs baseline: 1.1350x; 1.0487x over previous
//
#include <hip/hip_runtime.h>

#define HW    4096
#define DIMC  512
#define MEDC  1024
#define HRC   256
#define HSC   256
#define NBATCH 16

typedef __attribute__((ext_vector_type(8))) short bf16x8;
typedef __attribute__((ext_vector_type(4))) float f32x4;

// ---------------- workspace layout (floats) ----------------
static const size_t R1_OFF    = 0;
static const size_t XT_OFF    = 8388608;
static const size_t WCONV_OFF = 25165824;
static const size_t WR1_OFF   = 25755648;
static const size_t WRC_OFF   = 25821184;
static const size_t XP_OFF    = 0;
static const size_t WB1_OFF   = 67108864;
static const size_t WB2_OFF   = 67371008;
static const size_t MEAN_OFF  = 67633152;
static const size_t AGG_OFF   = MEAN_OFF + 4096;
static const size_t TAP_OFF   = AGG_OFF + 36864;
static const size_t ROUTE_OFF = TAP_OFF + 36864;
static const size_t SR_OFF    = ROUTE_OFF + 65536;
static const size_t WS_END    = SR_OFF + 65536;

__device__ __forceinline__ unsigned short f2bf(float f) {
  unsigned u = __float_as_uint(f);
  unsigned r = (u + 0x7fffu + ((u >> 16) & 1u)) >> 16;
  return (unsigned short)r;
}

// ---------------- generic f32 -> bf16 elementwise ----------------
__global__ __launch_bounds__(256) void cvt_bf16(
    const float* __restrict__ src, unsigned short* __restrict__ dst, int n)
{
  int i = blockIdx.x * 256 + threadIdx.x;
  if (i < n) dst[i] = f2bf(src[i]);
}

// ---------------- x [b][c][4096] f32 -> xT [b][pix][512] bf16 ----------------
__global__ __launch_bounds__(256) void xpose_bf16(
    const float* __restrict__ x, unsigned short* __restrict__ xT)
{
  __shared__ unsigned short T[32][33];
  const int tid = threadIdx.x;
  const int p0 = blockIdx.x * 32, c0 = blockIdx.y * 32, bb = blockIdx.z;
#pragma unroll
  for (int i = 0; i < 4; i++) {
    int idx = i * 256 + tid;
    int c_l = idx >> 5, p_l = idx & 31;
    T[c_l][p_l] = f2bf(x[((size_t)(bb * DIMC + c0 + c_l)) * HW + p0 + p_l]);
  }
  __syncthreads();
#pragma unroll
  for (int i = 0; i < 4; i++) {
    int idx = i * 256 + tid;
    int p_l = idx >> 5, c_l = idx & 31;
    xT[((size_t)bb * HW + p0 + p_l) * DIMC + c0 + c_l] = T[c_l][p_l];
  }
}

// ---------------- sp1w [o][c][9] f32 -> wconv [t][o][c] bf16 ----------------
__global__ __launch_bounds__(256) void wconv_bf16(
    const float* __restrict__ w, unsigned short* __restrict__ wbf)
{
  int idx = blockIdx.x * 256 + threadIdx.x;
  if (idx < HSC * DIMC) {
#pragma unroll
    for (int t = 0; t < 9; t++)
      wbf[(size_t)t * (HSC * DIMC) + idx] = f2bf(w[(size_t)idx * 9 + t]);
  }
}

// ---------------- bf16 MFMA GEMM, 128 pix x 128 n tile, 4 waves ----------------
template<int EPI, int ASRC>
__global__ __launch_bounds__(256) void gemm_bf16(
    const void* __restrict__ Aptr, const unsigned short* __restrict__ Wb,
    const float* __restrict__ bias, float* __restrict__ Cf,
    unsigned short* __restrict__ Cb, float* __restrict__ meansum,
    const float* __restrict__ star_scale, const float* __restrict__ star_bias,
    int K, int Ntot)
{
  __shared__ __align__(16) unsigned short As[128 * 40];
  __shared__ __align__(16) unsigned short Bs[128 * 40];
  const int tid = threadIdx.x;
  const int pix0 = blockIdx.x * 128;
  const int n0g = blockIdx.y * 128;
  const int bb = blockIdx.z;
  const int wid = tid >> 6, lane = tid & 63;
  const int lo = lane & 15, hi = lane >> 4;
  const int wm = wid >> 1, wn = wid & 1;

  f32x4 acc[4][4];
#pragma unroll
  for (int mi = 0; mi < 4; mi++)
#pragma unroll
    for (int ni = 0; ni < 4; ni++) acc[mi][ni] = (f32x4){0.f, 0.f, 0.f, 0.f};

  const int nsteps = K >> 5;
  for (int s = 0; s < nsteps; s++) {
    const int c0 = s * 32;
    if (ASRC == 0) {
      const unsigned short* AT = (const unsigned short*)Aptr;
#pragma unroll
      for (int it = 0; it < 2; it++) {
        int idx = it * 256 + tid;
        int p = idx >> 2, co = (idx & 3) * 8;
        uint4 v = *(const uint4*)&AT[((size_t)bb * HW + pix0 + p) * K + c0 + co];
        *(uint4*)&As[p * 40 + co] = v;
      }
    } else {
      const float* Af = (const float*)Aptr;
#pragma unroll
      for (int it = 0; it < 16; it++) {
        int idx = it * 256 + tid;
        int k_l = idx >> 7, p_l = idx & 127;
        float v = Af[((size_t)bb * K + c0 + k_l) * HW + pix0 + p_l];
        As[p_l * 40 + k_l] = f2bf(v);
      }
    }
#pragma unroll
    for (int it = 0; it < 2; it++) {
      int idx = it * 256 + tid;
      int o = idx >> 2, co = (idx & 3) * 8;
      uint4 v = *(const uint4*)&Wb[(size_t)(n0g + o) * K + c0 + co];
      *(uint4*)&Bs[o * 40 + co] = v;
    }
    __syncthreads();

    bf16x8 a[4], bq[4];
#pragma unroll
    for (int mi = 0; mi < 4; mi++)
      a[mi] = *(const bf16x8*)&As[(wm * 64 + mi * 16 + lo) * 40 + hi * 8];
#pragma unroll
    for (int ni = 0; ni < 4; ni++)
      bq[ni] = *(const bf16x8*)&Bs[(wn * 64 + ni * 16 + lo) * 40 + hi * 8];
#pragma unroll
    for (int mi = 0; mi < 4; mi++)
#pragma unroll
      for (int ni = 0; ni < 4; ni++)
        acc[mi][ni] = __builtin_amdgcn_mfma_f32_16x16x32_bf16(a[mi], bq[ni], acc[mi][ni], 0, 0, 0);
    __syncthreads();
  }

  if (EPI == 3) {
#pragma unroll
    for (int ni = 0; ni < 4; ni++) {
      const int n = n0g + wn * 64 + ni * 16 + lo;
      const float bia = bias[n];
      float T = 0.f;
#pragma unroll
      for (int mi = 0; mi < 4; mi++)
#pragma unroll
        for (int r = 0; r < 4; r++)
          T += fmaxf(acc[mi][ni][r] + bia, 0.f);
      T += __shfl_xor(T, 16);
      T += __shfl_xor(T, 32);
      if (hi == 0) atomicAdd(&meansum[bb * Ntot + n], T);
    }
    return;
  }

  if (EPI == 1) {
#pragma unroll
    for (int ni = 0; ni < 4; ni++) {
      const int n = n0g + wn * 64 + ni * 16 + lo;
      const float bia = bias[n];
#pragma unroll
      for (int mi = 0; mi < 4; mi++)
#pragma unroll
        for (int r = 0; r < 4; r++) {
          const int pix = pix0 + wm * 64 + mi * 16 + hi * 4 + r;
          Cb[((size_t)bb * HW + pix) * Ntot + n] = f2bf(fmaxf(acc[mi][ni][r] + bia, 0.f));
        }
    }
    return;
  }

  float ss = 1.f, sb = 0.f;
  if (EPI == 2) { ss = star_scale[0]; sb = star_bias[0]; }
#pragma unroll
  for (int ni = 0; ni < 4; ni++) {
    const int n = n0g + wn * 64 + ni * 16 + lo;
#pragma unroll
    for (int mi = 0; mi < 4; mi++) {
      const int pixb = pix0 + wm * 64 + mi * 16 + hi * 4;
      float4 v;
      float* vv = (float*)&v;
#pragma unroll
      for (int r = 0; r < 4; r++) {
        float t = acc[mi][ni][r];
        if (EPI == 2) { t = fmaxf(t, 0.f); t = ss * t * t + sb; }
        vv[r] = t;
      }
      *(float4*)&Cf[((size_t)bb * Ntot + n) * HW + pixb] = v;
    }
  }
}

// ---------------- sp_fc1 3x3 conv: halo-LDS implicit GEMM + relu + aggregates ----------------
// Per c-chunk: stage 4-row x 66-col x 32-c zero-padded halo ONCE; 9 taps read
// tap-shifted A-fragments directly from the halo. (Round-14 conv, unbundled.)
__global__ __launch_bounds__(256) void conv3_mfma(
    const unsigned short* __restrict__ xT, const unsigned short* __restrict__ wbf,
    const float* __restrict__ bias, float* __restrict__ agg)
{
  __shared__ __align__(16) unsigned short Xs[4 * 66 * 40];  // 21120 B
  __shared__ __align__(16) unsigned short Bs[128 * 40];     // 10240 B
  const int tid = threadIdx.x;
  const int bx = blockIdx.x;
  const int n0g = blockIdx.y * 128;
  const int bb = blockIdx.z;
  const int h0 = bx * 2;
  const int wid = tid >> 6;
  const int lane = tid & 63;
  const int lo = lane & 15, hi = lane >> 4;
  const int wm = wid >> 1;
  const int wn = wid & 1;

  f32x4 acc[4][4];
#pragma unroll
  for (int mi = 0; mi < 4; mi++)
#pragma unroll
    for (int ni = 0; ni < 4; ni++) acc[mi][ni] = (f32x4){0.f, 0.f, 0.f, 0.f};

  for (int ch = 0; ch < 16; ch++) {
    const int c0 = ch * 32;
    // stage A halo (1056 uint4): rows h0-1..h0+2, cols -1..64, zero-padded
#pragma unroll
    for (int it = 0; it < 5; it++) {
      int idx = it * 256 + tid;
      if (idx < 1056) {
        int pos = idx >> 2, q = idx & 3;
        int r = pos / 66, cc = pos - r * 66;
        int h = h0 + r - 1, col = cc - 1;
        uint4 v = make_uint4(0u, 0u, 0u, 0u);
        if (h >= 0 && h < 64 && col >= 0 && col < 64)
          v = *(const uint4*)&xT[((size_t)bb * HW + h * 64 + col) * DIMC + c0 + q * 8];
        *(uint4*)&Xs[pos * 40 + q * 8] = v;
      }
    }
#pragma unroll
    for (int t = 0; t < 9; t++) {
      const int di = t / 3 - 1, dj = t % 3 - 1;
#pragma unroll
      for (int it = 0; it < 2; it++) {
        int idx = it * 256 + tid;
        int o = idx >> 2, co = (idx & 3) * 8;
        uint4 v = *(const uint4*)&wbf[((size_t)t * (HSC * DIMC)) + (size_t)(n0g + o) * DIMC + c0 + co];
        *(uint4*)&Bs[o * 40 + co] = v;
      }
      __syncthreads();

      bf16x8 a[4], bfr[4];
#pragma unroll
      for (int mi = 0; mi < 4; mi++) {
        const int col = mi * 16 + lo;
        a[mi] = *(const bf16x8*)&Xs[((wm + di + 1) * 66 + col + dj + 1) * 40 + hi * 8];
      }
#pragma unroll
      for (int ni = 0; ni < 4; ni++)
        bfr[ni] = *(const bf16x8*)&Bs[(wn * 64 + ni * 16 + lo) * 40 + hi * 8];
#pragma unroll
      for (int mi = 0; mi < 4; mi++)
#pragma unroll
        for (int ni = 0; ni < 4; ni++)
          acc[mi][ni] = __builtin_amdgcn_mfma_f32_16x16x32_bf16(a[mi], bfr[ni], acc[mi][ni], 0, 0, 0);
      __syncthreads();
    }
  }

  const int h = h0 + wm;
#pragma unroll
  for (int ni = 0; ni < 4; ni++) {
    const int o = n0g + wn * 64 + ni * 16 + lo;
    const float bia = bias[o];
    float T = 0.f;
#pragma unroll
    for (int mi = 0; mi < 4; mi++)
#pragma unroll
      for (int r = 0; r < 4; r++)
        T += fmaxf(acc[mi][ni][r] + bia, 0.f);
    T += __shfl_xor(T, 16);
    T += __shfl_xor(T, 32);
    float* ag = &agg[((size_t)bb * HSC + o) * 9];
    if (hi == 0) {
      atomicAdd(ag + 0, T);
      if (h == 0)  atomicAdd(ag + 1, T);
      if (h == 63) atomicAdd(ag + 2, T);
      float c0v = fmaxf(acc[0][ni][0] + bia, 0.f);
      atomicAdd(ag + 3, c0v);
      if (h == 0)  atomicAdd(ag + 5, c0v);
      if (h == 63) atomicAdd(ag + 7, c0v);
    }
    if (hi == 3) {
      float cwv = fmaxf(acc[3][ni][3] + bia, 0.f);
      atomicAdd(ag + 4, cwv);
      if (h == 0)  atomicAdd(ag + 6, cwv);
      if (h == 63) atomicAdd(ag + 8, cwv);
    }
  }
}

// ---------------- aggregates -> 9 tap sums ----------------
__global__ void tap_compute(const float* __restrict__ agg, float* __restrict__ tap)
{
  int b = blockIdx.x; int c = threadIdx.x;
  const float* a = &agg[((size_t)b * HSC + c) * 9];
  float T = a[0], R0 = a[1], RH = a[2], C0 = a[3], CW = a[4];
  float s00 = a[5], s0W = a[6], sH0 = a[7], sHW = a[8];
  float* tp = &tap[((size_t)b * HSC + c) * 9];
#pragma unroll
  for (int i = 0; i < 3; i++)
#pragma unroll
    for (int j = 0; j < 3; j++) {
      int di = i - 1, dj = j - 1;
      float v = T;
      if (di == -1) v -= RH; else if (di == 1) v -= R0;
      if (dj == -1) v -= CW; else if (dj == 1) v -= C0;
      if (di == -1 && dj == -1) v += sHW;
      if (di == -1 && dj ==  1) v += sH0;
      if (di ==  1 && dj == -1) v += s0W;
      if (di ==  1 && dj ==  1) v += s00;
      tp[i * 3 + j] = v * (1.f / 4096.f);
    }
}

// ---------------- routing fc2 + softmax over NF ----------------
__global__ __launch_bounds__(256) void route_softmax(
    const float* __restrict__ meansum, const float* __restrict__ W,
    const float* __restrict__ bias, float* __restrict__ route)
{
  __shared__ float mv[HRC];
  int b = blockIdx.y;
  int m = blockIdx.x * 256 + threadIdx.x;
  mv[threadIdx.x] = meansum[b * HRC + threadIdx.x] * (1.f / 4096.f);
  __syncthreads();
  float l[4];
#pragma unroll
  for (int f = 0; f < 4; f++) {
    int o = f * MEDC + m;
    float accv = bias[o];
    const float* wr = &W[(size_t)o * HRC];
    for (int c = 0; c < HRC; c++) accv += wr[c] * mv[c];
    l[f] = accv;
  }
  float mx = fmaxf(fmaxf(l[0], l[1]), fmaxf(l[2], l[3]));
  float e[4], s = 0.f;
#pragma unroll
  for (int f = 0; f < 4; f++) { e[f] = expf(l[f] - mx); s += e[f]; }
  float inv = 1.f / s;
#pragma unroll
  for (int f = 0; f < 4; f++) route[((size_t)b * 4 + f) * MEDC + m] = e[f] * inv;
}

// ---------------- spatial routing fc2 (9-tap) + softmax ----------------
__global__ __launch_bounds__(256) void sproute_softmax(
    const float* __restrict__ tap, const float* __restrict__ W,
    const float* __restrict__ bias, float* __restrict__ sroute)
{
  __shared__ float tv[HSC * 9];
  int b = blockIdx.y;
  int m = blockIdx.x * 256 + threadIdx.x;
#pragma unroll
  for (int i = 0; i < 9; i++) {
    int idx = i * 256 + threadIdx.x;
    tv[idx] = tap[(size_t)b * HSC * 9 + idx];
  }
  __syncthreads();
  float l[4];
#pragma unroll
  for (int f = 0; f < 4; f++) {
    int o = f * MEDC + m;
    float accv = bias[o];
    const float* wr = &W[(size_t)o * HSC * 9];
    for (int ct = 0; ct < HSC * 9; ct++) accv += wr[ct] * tv[ct];
    l[f] = accv;
  }
  float mx = fmaxf(fmaxf(l[0], l[1]), fmaxf(l[2], l[3]));
  float e[4], s = 0.f;
#pragma unroll
  for (int f = 0; f < 4; f++) { e[f] = expf(l[f] - mx); s += e[f]; }
  float inv = 1.f / s;
#pragma unroll
  for (int f = 0; f < 4; f++) sroute[((size_t)b * 4 + f) * MEDC + m] = e[f] * inv;
}

// ---------------- compile-time twiddle tables: cos/sin(2*pi*a/64) ----------------
constexpr float TWC64[64] = {
  1.00000000f, 0.99518473f, 0.98078528f, 0.95694034f, 0.92387953f, 0.88192126f, 0.83146961f, 0.77301045f,
  0.70710678f, 0.63439328f, 0.55557023f, 0.47139674f, 0.38268343f, 0.29028468f, 0.19509032f, 0.09801714f,
  0.00000000f,-0.09801714f,-0.19509032f,-0.29028468f,-0.38268343f,-0.47139674f,-0.55557023f,-0.63439328f,
 -0.70710678f,-0.77301045f,-0.83146961f,-0.88192126f,-0.92387953f,-0.95694034f,-0.98078528f,-0.99518473f,
 -1.00000000f,-0.99518473f,-0.98078528f,-0.95694034f,-0.92387953f,-0.88192126f,-0.83146961f,-0.77301045f,
 -0.70710678f,-0.63439328f,-0.55557023f,-0.47139674f,-0.38268343f,-0.29028468f,-0.19509032f,-0.09801714f,
 -0.00000000f, 0.09801714f, 0.19509032f, 0.29028468f, 0.38268343f, 0.47139674f, 0.55557023f, 0.63439328f,
  0.70710678f, 0.77301045f, 0.83146961f, 0.88192126f, 0.92387953f, 0.95694034f, 0.98078528f, 0.99518473f
};
constexpr float TWS64[64] = {
  0.00000000f, 0.09801714f, 0.19509032f, 0.29028468f, 0.38268343f, 0.47139674f, 0.55557023f, 0.63439328f,
  0.70710678f, 0.77301045f, 0.83146961f, 0.88192126f, 0.92387953f, 0.95694034f, 0.98078528f, 0.99518473f,
  1.00000000f, 0.99518473f, 0.98078528f, 0.95694034f, 0.92387953f, 0.88192126f, 0.83146961f, 0.77301045f,
  0.70710678f, 0.63439328f, 0.55557023f, 0.47139674f, 0.38268343f, 0.29028468f, 0.19509032f, 0.09801714f,
  0.00000000f,-0.09801714f,-0.19509032f,-0.29028468f,-0.38268343f,-0.47139674f,-0.55557023f,-0.63439328f,
 -0.70710678f,-0.77301045f,-0.83146961f,-0.88192126f,-0.92387953f,-0.95694034f,-0.98078528f,-0.99518473f,
 -1.00000000f,-0.99518473f,-0.98078528f,-0.95694034f,-0.92387953f,-0.88192126f,-0.83146961f,-0.77301045f,
 -0.70710678f,-0.63439328f,-0.55557023f,-0.47139674f,-0.38268343f,-0.29028468f,-0.19509032f,-0.09801714f
};

// ---------------- radix-8 DFT helpers (register-resident) ----------------
template<int SGN>
__device__ __forceinline__ void dft8(const float* xr, const float* xi, float* Xr, float* Xi) {
  const float S = (float)SGN;
  const float r = 0.70710678118654752440f;
  float t0r = xr[0] + xr[4], t0i = xi[0] + xi[4];
  float t1r = xr[0] - xr[4], t1i = xi[0] - xi[4];
  float t2r = xr[2] + xr[6], t2i = xi[2] + xi[6];
  float t3r = xr[2] - xr[6], t3i = xi[2] - xi[6];
  float E0r = t0r + t2r, E0i = t0i + t2i;
  float E2r = t0r - t2r, E2i = t0i - t2i;
  float E1r = t1r - S * t3i, E1i = t1i + S * t3r;
  float E3r = t1r + S * t3i, E3i = t1i - S * t3r;
  float u0r = xr[1] + xr[5], u0i = xi[1] + xi[5];
  float u1r = xr[1] - xr[5], u1i = xi[1] - xi[5];
  float u2r = xr[3] + xr[7], u2i = xi[3] + xi[7];
  float u3r = xr[3] - xr[7], u3i = xi[3] - xi[7];
  float O0r = u0r + u2r, O0i = u0i + u2i;
  float O2r = u0r - u2r, O2i = u0i - u2i;
  float O1r = u1r - S * u3i, O1i = u1i + S * u3r;
  float O3r = u1r + S * u3i, O3i = u1i - S * u3r;
  float p1r = r * (O1r - S * O1i), p1i = r * (S * O1r + O1i);
  float p2r = -S * O2i,            p2i = S * O2r;
  float p3r = -r * (O3r + S * O3i), p3i = r * (S * O3r - O3i);
  Xr[0] = E0r + O0r; Xi[0] = E0i + O0i;
  Xr[4] = E0r - O0r; Xi[4] = E0i - O0i;
  Xr[1] = E1r + p1r; Xi[1] = E1i + p1i;
  Xr[5] = E1r - p1r; Xi[5] = E1i - p1i;
  Xr[2] = E2r + p2r; Xi[2] = E2i + p2i;
  Xr[6] = E2r - p2r; Xi[6] = E2i - p2i;
  Xr[3] = E3r + p3r; Xi[3] = E3i + p3i;
  Xr[7] = E3r - p3r; Xi[7] = E3i - p3i;
}

template<int SGN>
__device__ __forceinline__ void dft8_strided(float* xr, float* xi, const int base, const int stride) {
  float ar[8], ai[8], Br[8], Bi[8];
#pragma unroll
  for (int j = 0; j < 8; j++) { ar[j] = xr[base + j * stride]; ai[j] = xi[base + j * stride]; }
  dft8<SGN>(ar, ai, Br, Bi);
#pragma unroll
  for (int j = 0; j < 8; j++) { xr[base + j * stride] = Br[j]; xi[base + j * stride] = Bi[j]; }
}

template<int SGN>
__device__ __forceinline__ void twiddle_all(float* xr, float* xi) {
#pragma unroll
  for (int s = 0; s < 64; s++) {
    const int a = (s >> 3) * (s & 7);
    if (a) {
      const float c = TWC64[a];
      const float si = (float)SGN * TWS64[a];
      float rr = xr[s] * c - xi[s] * si;
      xi[s] = xr[s] * si + xi[s] * c;
      xr[s] = rr;
    }
  }
}

// 64-pt DFT, natural-order input -> digit-reversed output: slot 8*k1+k2 holds X[k1+8*k2].
template<int SGN>
__device__ __forceinline__ void fft64_n2r(float* xr, float* xi) {
#pragma unroll
  for (int g = 0; g < 8; g++) dft8_strided<SGN>(xr, xi, g, 8);
  twiddle_all<SGN>(xr, xi);
#pragma unroll
  for (int g = 0; g < 8; g++) dft8_strided<SGN>(xr, xi, 8 * g, 1);
}

// 64-pt DFT, digit-reversed input -> natural-order output.
template<int SGN>
__device__ __forceinline__ void fft64_r2n(float* xr, float* xi) {
#pragma unroll
  for (int g = 0; g < 8; g++) dft8_strided<SGN>(xr, xi, 8 * g, 1);
  twiddle_all<SGN>(xr, xi);
#pragma unroll
  for (int g = 0; g < 8; g++) dft8_strided<SGN>(xr, xi, g, 8);
}

// ---------------- FFT filter: 2 waves per block, 1 image per wave ----------------
__global__ __launch_bounds__(128, 1) void fft_filter(
    float* __restrict__ xp, const float* __restrict__ route,
    const float* __restrict__ sroute, const float* __restrict__ cw,
    const float* __restrict__ spw)
{
  __shared__ float Sbuf[2 * 64 * 66];   // 33792 B
  const int wave = threadIdx.x >> 6;
  const int lane = threadIdx.x & 63;
  float* S = &Sbuf[wave * (64 * 66)];
  float2* Fs = (float2*)S;
  const int blk = blockIdx.x * 2 + wave;
  const int b = blk >> 10;
  const int m = blk & 1023;
  float* img = xp + (size_t)blk * HW;

  float r4[4], s4[4];
#pragma unroll
  for (int f = 0; f < 4; f++) {
    r4[f] = route[((size_t)b * 4 + f) * MEDC + m] * (1.f / 4096.f);  // fold ortho norm
    s4[f] = sroute[((size_t)b * 4 + f) * MEDC + m];
  }

  // ==== stage in: coalesced global -> S (as X, stride 65) ====
#pragma unroll
  for (int t = 0; t < 16; t++) {
    const int idx = t * 64 + lane;
    float4 v = *(const float4*)&img[idx * 4];
    const int row = idx >> 4;
    const int col = (idx & 15) * 4;
    S[row * 65 + col + 0] = v.x;
    S[row * 65 + col + 1] = v.y;
    S[row * 65 + col + 2] = v.z;
    S[row * 65 + col + 3] = v.w;
  }
  __syncthreads();

  float xr[64], xi[64];

  // ==== pass 1: row forward rfft ====
#pragma unroll
  for (int w = 0; w < 64; w++) { xr[w] = S[lane * 65 + w]; xi[w] = 0.f; }
  __syncthreads();
  fft64_n2r<-1>(xr, xi);
#pragma unroll
  for (int k1 = 0; k1 < 8; k1++)
#pragma unroll
    for (int k2 = 0; k2 < 5; k2++) {
      const int k = k1 + 8 * k2;
      if (k <= 32)
        Fs[lane * 33 + k] = make_float2(xr[8 * k1 + k2], xi[8 * k1 + k2]);
    }
  __syncthreads();

  // ==== col pass: fwd fft + weight + inv fft, in registers (lane k < 33) ====
  if (lane < 33) {
#pragma unroll
    for (int h = 0; h < 64; h++) {
      float2 v = Fs[h * 33 + lane];
      xr[h] = v.x; xi[h] = v.y;
    }
    fft64_n2r<-1>(xr, xi);
#pragma unroll
    for (int s = 0; s < 64; s++) {
      const int kh = (s >> 3) + 8 * (s & 7);
      const float* cwp = &cw[(size_t)(kh * 33 + lane) * 8];
      float4 c0 = *(const float4*)cwp;
      float4 c1 = *(const float4*)(cwp + 4);
      float wre = r4[0] * c0.x + r4[1] * c0.z + r4[2] * c1.x + r4[3] * c1.z;
      float wim = r4[0] * c0.y + r4[1] * c0.w + r4[2] * c1.y + r4[3] * c1.w;
      float rr = xr[s] * wre - xi[s] * wim;
      xi[s] = xr[s] * wim + xi[s] * wre;
      xr[s] = rr;
    }
    fft64_r2n<1>(xr, xi);
#pragma unroll
    for (int h = 0; h < 64; h++)
      Fs[h * 33 + lane] = make_float2(xr[h], xi[h]);
  }
  __syncthreads();

  // ==== pass 4a: read spectrum row into registers (Hermitian pack) ====
#pragma unroll
  for (int k = 0; k < 33; k++) {
    float2 v = Fs[lane * 33 + k];
    if (k == 0 || k == 32) { xr[k] = v.x; xi[k] = 0.f; }
    else                   { xr[k] = 2.f * v.x; xi[k] = 2.f * v.y; }
  }
#pragma unroll
  for (int k = 33; k < 64; k++) { xr[k] = 0.f; xi[k] = 0.f; }
  __syncthreads();

  fft64_n2r<1>(xr, xi);

  // ==== re-stage img -> S (as X) for the gating term ====
#pragma unroll
  for (int t = 0; t < 16; t++) {
    const int idx = t * 64 + lane;
    float4 v = *(const float4*)&img[idx * 4];
    const int row = idx >> 4;
    const int col = (idx & 15) * 4;
    S[row * 65 + col + 0] = v.x;
    S[row * 65 + col + 1] = v.y;
    S[row * 65 + col + 2] = v.z;
    S[row * 65 + col + 3] = v.w;
  }
  __syncthreads();

  // ==== pass 4b: gating + add, write own row back into S ====
#pragma unroll
  for (int w = 0; w < 64; w++) {
    const int s = 8 * (w & 7) + (w >> 3);
    float4 sp = *(const float4*)&spw[(size_t)(lane * 64 + w) * 4];
    float sw = s4[0] * sp.x + s4[1] * sp.y + s4[2] * sp.z + s4[3] * sp.w;
    S[lane * 65 + w] = S[lane * 65 + w] * sw + xr[s];
  }
  __syncthreads();

  // ==== stage out: S -> coalesced global ====
#pragma unroll
  for (int t = 0; t < 16; t++) {
    const int idx = t * 64 + lane;
    const int row = idx >> 4;
    const int col = (idx & 15) * 4;
    float4 o;
    o.x = S[row * 65 + col + 0];
    o.y = S[row * 65 + col + 1];
    o.z = S[row * 65 + col + 2];
    o.w = S[row * 65 + col + 3];
    *(float4*)&img[idx * 4] = o;
  }
}

extern "C" void kernel_launch(void* const* d_in, const int* in_sizes, int n_in,
                              void* d_out, int out_size, void* d_ws, size_t ws_size,
                              hipStream_t stream) {
  const float* x          = (const float*)d_in[0];
  const float* w_pw1      = (const float*)d_in[1];
  const float* w_pw2      = (const float*)d_in[2];
  const float* star_scale = (const float*)d_in[3];
  const float* star_bias  = (const float*)d_in[4];
  const float* rw1w = (const float*)d_in[5];
  const float* rw1b = (const float*)d_in[6];
  const float* rwcw = (const float*)d_in[7];
  const float* rwcb = (const float*)d_in[8];
  const float* rw2w = (const float*)d_in[9];
  const float* rw2b = (const float*)d_in[10];
  const float* sp1w = (const float*)d_in[11];
  const float* sp1b = (const float*)d_in[12];
  const float* sp2w = (const float*)d_in[13];
  const float* sp2b = (const float*)d_in[14];
  const float* cw   = (const float*)d_in[15];
  const float* spw  = (const float*)d_in[16];

  if (ws_size < WS_END * sizeof(float)) return;

  float* ws = (float*)d_ws;
  float* xp = ws + XP_OFF;
  unsigned short* r1    = (unsigned short*)(ws + R1_OFF);
  unsigned short* xT    = (unsigned short*)(ws + XT_OFF);
  unsigned short* wconv = (unsigned short*)(ws + WCONV_OFF);
  unsigned short* wr1   = (unsigned short*)(ws + WR1_OFF);
  unsigned short* wrc   = (unsigned short*)(ws + WRC_OFF);
  unsigned short* wb1   = (unsigned short*)(ws + WB1_OFF);
  unsigned short* wb2   = (unsigned short*)(ws + WB2_OFF);
  float* meansum = ws + MEAN_OFF;
  float* agg     = ws + AGG_OFF;
  float* tap     = ws + TAP_OFF;
  float* route   = ws + ROUTE_OFF;
  float* sr      = ws + SR_OFF;
  float* out = (float*)d_out;

  hipMemsetAsync(meansum, 0, (4096 + 36864) * sizeof(float), stream);

  // bf16 prep
  xpose_bf16<<<dim3(128, 16, 16), 256, 0, stream>>>(x, xT);
  wconv_bf16<<<512, 256, 0, stream>>>(sp1w, wconv);
  cvt_bf16<<<2048, 256, 0, stream>>>(w_pw1, wb1, MEDC * DIMC);
  cvt_bf16<<<2048, 256, 0, stream>>>(w_pw2, wb2, DIMC * MEDC);
  cvt_bf16<<<512, 256, 0, stream>>>(rw1w, wr1, HRC * DIMC);
  cvt_bf16<<<256, 256, 0, stream>>>(rwcw, wrc, HRC * HRC);

  // routing branch (bf16 MFMA)
  gemm_bf16<1, 0><<<dim3(32, 2, 16), 256, 0, stream>>>(
      xT, wr1, rw1b, nullptr, r1, nullptr, nullptr, nullptr, DIMC, HRC);
  gemm_bf16<3, 0><<<dim3(32, 2, 16), 256, 0, stream>>>(
      r1, wrc, rwcb, nullptr, nullptr, meansum, nullptr, nullptr, HRC, HRC);
  route_softmax<<<dim3(4, 16), 256, 0, stream>>>(meansum, rw2w, rw2b, route);

  // spatial routing branch (bf16 MFMA conv, halo-LDS)
  conv3_mfma<<<dim3(32, 2, 16), 256, 0, stream>>>(xT, wconv, sp1b, agg);
  tap_compute<<<16, 256, 0, stream>>>(agg, tap);
  sproute_softmax<<<dim3(4, 16), 256, 0, stream>>>(tap, sp2w, sp2b, sr);

  // main path (bf16 MFMA) — pw1 reads f32 x (ASRC1): xT aliases the xp region (race if ASRC0)
  gemm_bf16<2, 1><<<dim3(32, 8, 16), 256, 0, stream>>>(
      x, wb1, nullptr, xp, nullptr, nullptr, star_scale, star_bias, DIMC, MEDC);
  fft_filter<<<8192, 128, 0, stream>>>(xp, route, sr, cw, spw);
  gemm_bf16<0, 1><<<dim3(32, 4, 16), 256, 0, stream>>>(
      xp, wb2, nullptr, out, nullptr, nullptr, nullptr, nullptr, MEDC, DIMC);
}

// Round 17
// 1497.268 us; speedup vs baseline: 1.1864x; 1.0453x over previous
//
#include <hip/hip_runtime.h>

#define HW    4096
#define DIMC  512
#define MEDC  1024
#define HRC   256
#define HSC   256
#define NBATCH 16

typedef __attribute__((ext_vector_type(8))) short bf16x8;
typedef __attribute__((ext_vector_type(4))) float f32x4;

// ---------------- workspace layout (floats) ----------------
static const size_t R1_OFF    = 0;
static const size_t XT_OFF    = 8388608;           // aliased layout: xT inside xp region
static const size_t WCONV_OFF = 25165824;
static const size_t WR1_OFF   = 25755648;
static const size_t WRC_OFF   = 25821184;
static const size_t XP_OFF    = 0;
static const size_t WB1_OFF   = 67108864;
static const size_t WB2_OFF   = 67371008;
static const size_t MEAN_OFF  = 67633152;
static const size_t AGG_OFF   = MEAN_OFF + 4096;
static const size_t TAP_OFF   = AGG_OFF + 36864;
static const size_t ROUTE_OFF = TAP_OFF + 36864;
static const size_t SR_OFF    = ROUTE_OFF + 65536;
static const size_t WS_END    = SR_OFF + 65536;
static const size_t XT2_OFF   = WS_END;            // disjoint layout: xT past everything
static const size_t WS_END2   = XT2_OFF + 16777216;

__device__ __forceinline__ unsigned short f2bf(float f) {
  unsigned u = __float_as_uint(f);
  unsigned r = (u + 0x7fffu + ((u >> 16) & 1u)) >> 16;
  return (unsigned short)r;
}

// ---------------- generic f32 -> bf16 elementwise ----------------
__global__ __launch_bounds__(256) void cvt_bf16(
    const float* __restrict__ src, unsigned short* __restrict__ dst, int n)
{
  int i = blockIdx.x * 256 + threadIdx.x;
  if (i < n) dst[i] = f2bf(src[i]);
}

// ---------------- x [b][c][4096] f32 -> xT [b][pix][512] bf16 ----------------
__global__ __launch_bounds__(256) void xpose_bf16(
    const float* __restrict__ x, unsigned short* __restrict__ xT)
{
  __shared__ unsigned short T[32][33];
  const int tid = threadIdx.x;
  const int p0 = blockIdx.x * 32, c0 = blockIdx.y * 32, bb = blockIdx.z;
#pragma unroll
  for (int i = 0; i < 4; i++) {
    int idx = i * 256 + tid;
    int c_l = idx >> 5, p_l = idx & 31;
    T[c_l][p_l] = f2bf(x[((size_t)(bb * DIMC + c0 + c_l)) * HW + p0 + p_l]);
  }
  __syncthreads();
#pragma unroll
  for (int i = 0; i < 4; i++) {
    int idx = i * 256 + tid;
    int p_l = idx >> 5, c_l = idx & 31;
    xT[((size_t)bb * HW + p0 + p_l) * DIMC + c0 + c_l] = T[c_l][p_l];
  }
}

// ---------------- sp1w [o][c][9] f32 -> wconv [t][o][c] bf16 ----------------
__global__ __launch_bounds__(256) void wconv_bf16(
    const float* __restrict__ w, unsigned short* __restrict__ wbf)
{
  int idx = blockIdx.x * 256 + threadIdx.x;
  if (idx < HSC * DIMC) {
#pragma unroll
    for (int t = 0; t < 9; t++)
      wbf[(size_t)t * (HSC * DIMC) + idx] = f2bf(w[(size_t)idx * 9 + t]);
  }
}

// ---------------- bf16 MFMA GEMM, 128 pix x 128 n tile, 4 waves ----------------
template<int EPI, int ASRC>
__global__ __launch_bounds__(256) void gemm_bf16(
    const void* __restrict__ Aptr, const unsigned short* __restrict__ Wb,
    const float* __restrict__ bias, float* __restrict__ Cf,
    unsigned short* __restrict__ Cb, float* __restrict__ meansum,
    const float* __restrict__ star_scale, const float* __restrict__ star_bias,
    int K, int Ntot)
{
  __shared__ __align__(16) unsigned short As[128 * 40];
  __shared__ __align__(16) unsigned short Bs[128 * 40];
  const int tid = threadIdx.x;
  const int pix0 = blockIdx.x * 128;
  const int n0g = blockIdx.y * 128;
  const int bb = blockIdx.z;
  const int wid = tid >> 6, lane = tid & 63;
  const int lo = lane & 15, hi = lane >> 4;
  const int wm = wid >> 1, wn = wid & 1;

  f32x4 acc[4][4];
#pragma unroll
  for (int mi = 0; mi < 4; mi++)
#pragma unroll
    for (int ni = 0; ni < 4; ni++) acc[mi][ni] = (f32x4){0.f, 0.f, 0.f, 0.f};

  const int nsteps = K >> 5;
  for (int s = 0; s < nsteps; s++) {
    const int c0 = s * 32;
    if (ASRC == 0) {
      const unsigned short* AT = (const unsigned short*)Aptr;
#pragma unroll
      for (int it = 0; it < 2; it++) {
        int idx = it * 256 + tid;
        int p = idx >> 2, co = (idx & 3) * 8;
        uint4 v = *(const uint4*)&AT[((size_t)bb * HW + pix0 + p) * K + c0 + co];
        *(uint4*)&As[p * 40 + co] = v;
      }
    } else {
      const float* Af = (const float*)Aptr;
#pragma unroll
      for (int it = 0; it < 16; it++) {
        int idx = it * 256 + tid;
        int k_l = idx >> 7, p_l = idx & 127;
        float v = Af[((size_t)bb * K + c0 + k_l) * HW + pix0 + p_l];
        As[p_l * 40 + k_l] = f2bf(v);
      }
    }
#pragma unroll
    for (int it = 0; it < 2; it++) {
      int idx = it * 256 + tid;
      int o = idx >> 2, co = (idx & 3) * 8;
      uint4 v = *(const uint4*)&Wb[(size_t)(n0g + o) * K + c0 + co];
      *(uint4*)&Bs[o * 40 + co] = v;
    }
    __syncthreads();

    bf16x8 a[4], bq[4];
#pragma unroll
    for (int mi = 0; mi < 4; mi++)
      a[mi] = *(const bf16x8*)&As[(wm * 64 + mi * 16 + lo) * 40 + hi * 8];
#pragma unroll
    for (int ni = 0; ni < 4; ni++)
      bq[ni] = *(const bf16x8*)&Bs[(wn * 64 + ni * 16 + lo) * 40 + hi * 8];
#pragma unroll
    for (int mi = 0; mi < 4; mi++)
#pragma unroll
      for (int ni = 0; ni < 4; ni++)
        acc[mi][ni] = __builtin_amdgcn_mfma_f32_16x16x32_bf16(a[mi], bq[ni], acc[mi][ni], 0, 0, 0);
    __syncthreads();
  }

  if (EPI == 3) {
#pragma unroll
    for (int ni = 0; ni < 4; ni++) {
      const int n = n0g + wn * 64 + ni * 16 + lo;
      const float bia = bias[n];
      float T = 0.f;
#pragma unroll
      for (int mi = 0; mi < 4; mi++)
#pragma unroll
        for (int r = 0; r < 4; r++)
          T += fmaxf(acc[mi][ni][r] + bia, 0.f);
      T += __shfl_xor(T, 16);
      T += __shfl_xor(T, 32);
      if (hi == 0) atomicAdd(&meansum[bb * Ntot + n], T);
    }
    return;
  }

  if (EPI == 1) {
#pragma unroll
    for (int ni = 0; ni < 4; ni++) {
      const int n = n0g + wn * 64 + ni * 16 + lo;
      const float bia = bias[n];
#pragma unroll
      for (int mi = 0; mi < 4; mi++)
#pragma unroll
        for (int r = 0; r < 4; r++) {
          const int pix = pix0 + wm * 64 + mi * 16 + hi * 4 + r;
          Cb[((size_t)bb * HW + pix) * Ntot + n] = f2bf(fmaxf(acc[mi][ni][r] + bia, 0.f));
        }
    }
    return;
  }

  float ss = 1.f, sb = 0.f;
  if (EPI == 2) { ss = star_scale[0]; sb = star_bias[0]; }
#pragma unroll
  for (int ni = 0; ni < 4; ni++) {
    const int n = n0g + wn * 64 + ni * 16 + lo;
#pragma unroll
    for (int mi = 0; mi < 4; mi++) {
      const int pixb = pix0 + wm * 64 + mi * 16 + hi * 4;
      float4 v;
      float* vv = (float*)&v;
#pragma unroll
      for (int r = 0; r < 4; r++) {
        float t = acc[mi][ni][r];
        if (EPI == 2) { t = fmaxf(t, 0.f); t = ss * t * t + sb; }
        vv[r] = t;
      }
      *(float4*)&Cf[((size_t)bb * Ntot + n) * HW + pixb] = v;
    }
  }
}

// ---------------- sp_fc1 3x3 conv: halo-LDS implicit GEMM + relu + aggregates ----------------
__global__ __launch_bounds__(256) void conv3_mfma(
    const unsigned short* __restrict__ xT, const unsigned short* __restrict__ wbf,
    const float* __restrict__ bias, float* __restrict__ agg)
{
  __shared__ __align__(16) unsigned short Xs[4 * 66 * 40];  // 21120 B
  __shared__ __align__(16) unsigned short Bs[128 * 40];     // 10240 B
  const int tid = threadIdx.x;
  const int bx = blockIdx.x;
  const int n0g = blockIdx.y * 128;
  const int bb = blockIdx.z;
  const int h0 = bx * 2;
  const int wid = tid >> 6;
  const int lane = tid & 63;
  const int lo = lane & 15, hi = lane >> 4;
  const int wm = wid >> 1;
  const int wn = wid & 1;

  f32x4 acc[4][4];
#pragma unroll
  for (int mi = 0; mi < 4; mi++)
#pragma unroll
    for (int ni = 0; ni < 4; ni++) acc[mi][ni] = (f32x4){0.f, 0.f, 0.f, 0.f};

  for (int ch = 0; ch < 16; ch++) {
    const int c0 = ch * 32;
#pragma unroll
    for (int it = 0; it < 5; it++) {
      int idx = it * 256 + tid;
      if (idx < 1056) {
        int pos = idx >> 2, q = idx & 3;
        int r = pos / 66, cc = pos - r * 66;
        int h = h0 + r - 1, col = cc - 1;
        uint4 v = make_uint4(0u, 0u, 0u, 0u);
        if (h >= 0 && h < 64 && col >= 0 && col < 64)
          v = *(const uint4*)&xT[((size_t)bb * HW + h * 64 + col) * DIMC + c0 + q * 8];
        *(uint4*)&Xs[pos * 40 + q * 8] = v;
      }
    }
#pragma unroll
    for (int t = 0; t < 9; t++) {
      const int di = t / 3 - 1, dj = t % 3 - 1;
#pragma unroll
      for (int it = 0; it < 2; it++) {
        int idx = it * 256 + tid;
        int o = idx >> 2, co = (idx & 3) * 8;
        uint4 v = *(const uint4*)&wbf[((size_t)t * (HSC * DIMC)) + (size_t)(n0g + o) * DIMC + c0 + co];
        *(uint4*)&Bs[o * 40 + co] = v;
      }
      __syncthreads();

      bf16x8 a[4], bfr[4];
#pragma unroll
      for (int mi = 0; mi < 4; mi++) {
        const int col = mi * 16 + lo;
        a[mi] = *(const bf16x8*)&Xs[((wm + di + 1) * 66 + col + dj + 1) * 40 + hi * 8];
      }
#pragma unroll
      for (int ni = 0; ni < 4; ni++)
        bfr[ni] = *(const bf16x8*)&Bs[(wn * 64 + ni * 16 + lo) * 40 + hi * 8];
#pragma unroll
      for (int mi = 0; mi < 4; mi++)
#pragma unroll
        for (int ni = 0; ni < 4; ni++)
          acc[mi][ni] = __builtin_amdgcn_mfma_f32_16x16x32_bf16(a[mi], bfr[ni], acc[mi][ni], 0, 0, 0);
      __syncthreads();
    }
  }

  const int h = h0 + wm;
#pragma unroll
  for (int ni = 0; ni < 4; ni++) {
    const int o = n0g + wn * 64 + ni * 16 + lo;
    const float bia = bias[o];
    float T = 0.f;
#pragma unroll
    for (int mi = 0; mi < 4; mi++)
#pragma unroll
      for (int r = 0; r < 4; r++)
        T += fmaxf(acc[mi][ni][r] + bia, 0.f);
    T += __shfl_xor(T, 16);
    T += __shfl_xor(T, 32);
    float* ag = &agg[((size_t)bb * HSC + o) * 9];
    if (hi == 0) {
      atomicAdd(ag + 0, T);
      if (h == 0)  atomicAdd(ag + 1, T);
      if (h == 63) atomicAdd(ag + 2, T);
      float c0v = fmaxf(acc[0][ni][0] + bia, 0.f);
      atomicAdd(ag + 3, c0v);
      if (h == 0)  atomicAdd(ag + 5, c0v);
      if (h == 63) atomicAdd(ag + 7, c0v);
    }
    if (hi == 3) {
      float cwv = fmaxf(acc[3][ni][3] + bia, 0.f);
      atomicAdd(ag + 4, cwv);
      if (h == 0)  atomicAdd(ag + 6, cwv);
      if (h == 63) atomicAdd(ag + 8, cwv);
    }
  }
}

// ---------------- aggregates -> 9 tap sums ----------------
__global__ void tap_compute(const float* __restrict__ agg, float* __restrict__ tap)
{
  int b = blockIdx.x; int c = threadIdx.x;
  const float* a = &agg[((size_t)b * HSC + c) * 9];
  float T = a[0], R0 = a[1], RH = a[2], C0 = a[3], CW = a[4];
  float s00 = a[5], s0W = a[6], sH0 = a[7], sHW = a[8];
  float* tp = &tap[((size_t)b * HSC + c) * 9];
#pragma unroll
  for (int i = 0; i < 3; i++)
#pragma unroll
    for (int j = 0; j < 3; j++) {
      int di = i - 1, dj = j - 1;
      float v = T;
      if (di == -1) v -= RH; else if (di == 1) v -= R0;
      if (dj == -1) v -= CW; else if (dj == 1) v -= C0;
      if (di == -1 && dj == -1) v += sHW;
      if (di == -1 && dj ==  1) v += sH0;
      if (di ==  1 && dj == -1) v += s0W;
      if (di ==  1 && dj ==  1) v += s00;
      tp[i * 3 + j] = v * (1.f / 4096.f);
    }
}

// ---------------- routing fc2 + softmax over NF ----------------
__global__ __launch_bounds__(256) void route_softmax(
    const float* __restrict__ meansum, const float* __restrict__ W,
    const float* __restrict__ bias, float* __restrict__ route)
{
  __shared__ float mv[HRC];
  int b = blockIdx.y;
  int m = blockIdx.x * 256 + threadIdx.x;
  mv[threadIdx.x] = meansum[b * HRC + threadIdx.x] * (1.f / 4096.f);
  __syncthreads();
  float l[4];
#pragma unroll
  for (int f = 0; f < 4; f++) {
    int o = f * MEDC + m;
    float accv = bias[o];
    const float* wr = &W[(size_t)o * HRC];
    for (int c = 0; c < HRC; c++) accv += wr[c] * mv[c];
    l[f] = accv;
  }
  float mx = fmaxf(fmaxf(l[0], l[1]), fmaxf(l[2], l[3]));
  float e[4], s = 0.f;
#pragma unroll
  for (int f = 0; f < 4; f++) { e[f] = expf(l[f] - mx); s += e[f]; }
  float inv = 1.f / s;
#pragma unroll
  for (int f = 0; f < 4; f++) route[((size_t)b * 4 + f) * MEDC + m] = e[f] * inv;
}

// ---------------- spatial routing fc2 (9-tap) + softmax ----------------
__global__ __launch_bounds__(256) void sproute_softmax(
    const float* __restrict__ tap, const float* __restrict__ W,
    const float* __restrict__ bias, float* __restrict__ sroute)
{
  __shared__ float tv[HSC * 9];
  int b = blockIdx.y;
  int m = blockIdx.x * 256 + threadIdx.x;
#pragma unroll
  for (int i = 0; i < 9; i++) {
    int idx = i * 256 + threadIdx.x;
    tv[idx] = tap[(size_t)b * HSC * 9 + idx];
  }
  __syncthreads();
  float l[4];
#pragma unroll
  for (int f = 0; f < 4; f++) {
    int o = f * MEDC + m;
    float accv = bias[o];
    const float* wr = &W[(size_t)o * HSC * 9];
    for (int ct = 0; ct < HSC * 9; ct++) accv += wr[ct] * tv[ct];
    l[f] = accv;
  }
  float mx = fmaxf(fmaxf(l[0], l[1]), fmaxf(l[2], l[3]));
  float e[4], s = 0.f;
#pragma unroll
  for (int f = 0; f < 4; f++) { e[f] = expf(l[f] - mx); s += e[f]; }
  float inv = 1.f / s;
#pragma unroll
  for (int f = 0; f < 4; f++) sroute[((size_t)b * 4 + f) * MEDC + m] = e[f] * inv;
}

// ---------------- compile-time twiddle tables: cos/sin(2*pi*a/64) ----------------
constexpr float TWC64[64] = {
  1.00000000f, 0.99518473f, 0.98078528f, 0.95694034f, 0.92387953f, 0.88192126f, 0.83146961f, 0.77301045f,
  0.70710678f, 0.63439328f, 0.55557023f, 0.47139674f, 0.38268343f, 0.29028468f, 0.19509032f, 0.09801714f,
  0.00000000f,-0.09801714f,-0.19509032f,-0.29028468f,-0.38268343f,-0.47139674f,-0.55557023f,-0.63439328f,
 -0.70710678f,-0.77301045f,-0.83146961f,-0.88192126f,-0.92387953f,-0.95694034f,-0.98078528f,-0.99518473f,
 -1.00000000f,-0.99518473f,-0.98078528f,-0.95694034f,-0.92387953f,-0.88192126f,-0.83146961f,-0.77301045f,
 -0.70710678f,-0.63439328f,-0.55557023f,-0.47139674f,-0.38268343f,-0.29028468f,-0.19509032f,-0.09801714f,
 -0.00000000f, 0.09801714f, 0.19509032f, 0.29028468f, 0.38268343f, 0.47139674f, 0.55557023f, 0.63439328f,
  0.70710678f, 0.77301045f, 0.83146961f, 0.88192126f, 0.92387953f, 0.95694034f, 0.98078528f, 0.99518473f
};
constexpr float TWS64[64] = {
  0.00000000f, 0.09801714f, 0.19509032f, 0.29028468f, 0.38268343f, 0.47139674f, 0.55557023f, 0.63439328f,
  0.70710678f, 0.77301045f, 0.83146961f, 0.88192126f, 0.92387953f, 0.95694034f, 0.98078528f, 0.99518473f,
  1.00000000f, 0.99518473f, 0.98078528f, 0.95694034f, 0.92387953f, 0.88192126f, 0.83146961f, 0.77301045f,
  0.70710678f, 0.63439328f, 0.55557023f, 0.47139674f, 0.38268343f, 0.29028468f, 0.19509032f, 0.09801714f,
  0.00000000f,-0.09801714f,-0.19509032f,-0.29028468f,-0.38268343f,-0.47139674f,-0.55557023f,-0.63439328f,
 -0.70710678f,-0.77301045f,-0.83146961f,-0.88192126f,-0.92387953f,-0.95694034f,-0.98078528f,-0.99518473f,
 -1.00000000f,-0.99518473f,-0.98078528f,-0.95694034f,-0.92387953f,-0.88192126f,-0.83146961f,-0.77301045f,
 -0.70710678f,-0.63439328f,-0.55557023f,-0.47139674f,-0.38268343f,-0.29028468f,-0.19509032f,-0.09801714f
};

// ---------------- radix-8 DFT helpers (register-resident) ----------------
template<int SGN>
__device__ __forceinline__ void dft8(const float* xr, const float* xi, float* Xr, float* Xi) {
  const float S = (float)SGN;
  const float r = 0.70710678118654752440f;
  float t0r = xr[0] + xr[4], t0i = xi[0] + xi[4];
  float t1r = xr[0] - xr[4], t1i = xi[0] - xi[4];
  float t2r = xr[2] + xr[6], t2i = xi[2] + xi[6];
  float t3r = xr[2] - xr[6], t3i = xi[2] - xi[6];
  float E0r = t0r + t2r, E0i = t0i + t2i;
  float E2r = t0r - t2r, E2i = t0i - t2i;
  float E1r = t1r - S * t3i, E1i = t1i + S * t3r;
  float E3r = t1r + S * t3i, E3i = t1i - S * t3r;
  float u0r = xr[1] + xr[5], u0i = xi[1] + xi[5];
  float u1r = xr[1] - xr[5], u1i = xi[1] - xi[5];
  float u2r = xr[3] + xr[7], u2i = xi[3] + xi[7];
  float u3r = xr[3] - xr[7], u3i = xi[3] - xi[7];
  float O0r = u0r + u2r, O0i = u0i + u2i;
  float O2r = u0r - u2r, O2i = u0i - u2i;
  float O1r = u1r - S * u3i, O1i = u1i + S * u3r;
  float O3r = u1r + S * u3i, O3i = u1i - S * u3r;
  float p1r = r * (O1r - S * O1i), p1i = r * (S * O1r + O1i);
  float p2r = -S * O2i,            p2i = S * O2r;
  float p3r = -r * (O3r + S * O3i), p3i = r * (S * O3r - O3i);
  Xr[0] = E0r + O0r; Xi[0] = E0i + O0i;
  Xr[4] = E0r - O0r; Xi[4] = E0i - O0i;
  Xr[1] = E1r + p1r; Xi[1] = E1i + p1i;
  Xr[5] = E1r - p1r; Xi[5] = E1i - p1i;
  Xr[2] = E2r + p2r; Xi[2] = E2i + p2i;
  Xr[6] = E2r - p2r; Xi[6] = E2i - p2i;
  Xr[3] = E3r + p3r; Xi[3] = E3i + p3i;
  Xr[7] = E3r - p3r; Xi[7] = E3i - p3i;
}

template<int SGN>
__device__ __forceinline__ void dft8_strided(float* xr, float* xi, const int base, const int stride) {
  float ar[8], ai[8], Br[8], Bi[8];
#pragma unroll
  for (int j = 0; j < 8; j++) { ar[j] = xr[base + j * stride]; ai[j] = xi[base + j * stride]; }
  dft8<SGN>(ar, ai, Br, Bi);
#pragma unroll
  for (int j = 0; j < 8; j++) { xr[base + j * stride] = Br[j]; xi[base + j * stride] = Bi[j]; }
}

template<int SGN>
__device__ __forceinline__ void twiddle_all(float* xr, float* xi) {
#pragma unroll
  for (int s = 0; s < 64; s++) {
    const int a = (s >> 3) * (s & 7);
    if (a) {
      const float c = TWC64[a];
      const float si = (float)SGN * TWS64[a];
      float rr = xr[s] * c - xi[s] * si;
      xi[s] = xr[s] * si + xi[s] * c;
      xr[s] = rr;
    }
  }
}

// 64-pt DFT, natural-order input -> digit-reversed output: slot 8*k1+k2 holds X[k1+8*k2].
template<int SGN>
__device__ __forceinline__ void fft64_n2r(float* xr, float* xi) {
#pragma unroll
  for (int g = 0; g < 8; g++) dft8_strided<SGN>(xr, xi, g, 8);
  twiddle_all<SGN>(xr, xi);
#pragma unroll
  for (int g = 0; g < 8; g++) dft8_strided<SGN>(xr, xi, 8 * g, 1);
}

// 64-pt DFT, digit-reversed input -> natural-order output.
template<int SGN>
__device__ __forceinline__ void fft64_r2n(float* xr, float* xi) {
#pragma unroll
  for (int g = 0; g < 8; g++) dft8_strided<SGN>(xr, xi, 8 * g, 1);
  twiddle_all<SGN>(xr, xi);
#pragma unroll
  for (int g = 0; g < 8; g++) dft8_strided<SGN>(xr, xi, g, 8);
}

// ---------------- FFT filter: 2 waves per block, 1 image per wave ----------------
__global__ __launch_bounds__(128, 1) void fft_filter(
    float* __restrict__ xp, const float* __restrict__ route,
    const float* __restrict__ sroute, const float* __restrict__ cw,
    const float* __restrict__ spw)
{
  __shared__ float Sbuf[2 * 64 * 66];   // 33792 B
  const int wave = threadIdx.x >> 6;
  const int lane = threadIdx.x & 63;
  float* S = &Sbuf[wave * (64 * 66)];
  float2* Fs = (float2*)S;
  const int blk = blockIdx.x * 2 + wave;
  const int b = blk >> 10;
  const int m = blk & 1023;
  float* img = xp + (size_t)blk * HW;

  float r4[4], s4[4];
#pragma unroll
  for (int f = 0; f < 4; f++) {
    r4[f] = route[((size_t)b * 4 + f) * MEDC + m] * (1.f / 4096.f);  // fold ortho norm
    s4[f] = sroute[((size_t)b * 4 + f) * MEDC + m];
  }

  // ==== stage in: coalesced global -> S (as X, stride 65) ====
#pragma unroll
  for (int t = 0; t < 16; t++) {
    const int idx = t * 64 + lane;
    float4 v = *(const float4*)&img[idx * 4];
    const int row = idx >> 4;
    const int col = (idx & 15) * 4;
    S[row * 65 + col + 0] = v.x;
    S[row * 65 + col + 1] = v.y;
    S[row * 65 + col + 2] = v.z;
    S[row * 65 + col + 3] = v.w;
  }
  __syncthreads();

  float xr[64], xi[64];

  // ==== pass 1: row forward rfft ====
#pragma unroll
  for (int w = 0; w < 64; w++) { xr[w] = S[lane * 65 + w]; xi[w] = 0.f; }
  __syncthreads();
  fft64_n2r<-1>(xr, xi);
#pragma unroll
  for (int k1 = 0; k1 < 8; k1++)
#pragma unroll
    for (int k2 = 0; k2 < 5; k2++) {
      const int k = k1 + 8 * k2;
      if (k <= 32)
        Fs[lane * 33 + k] = make_float2(xr[8 * k1 + k2], xi[8 * k1 + k2]);
    }
  __syncthreads();

  // ==== col pass: fwd fft + weight + inv fft, in registers (lane k < 33) ====
  if (lane < 33) {
#pragma unroll
    for (int h = 0; h < 64; h++) {
      float2 v = Fs[h * 33 + lane];
      xr[h] = v.x; xi[h] = v.y;
    }
    fft64_n2r<-1>(xr, xi);
#pragma unroll
    for (int s = 0; s < 64; s++) {
      const int kh = (s >> 3) + 8 * (s & 7);
      const float* cwp = &cw[(size_t)(kh * 33 + lane) * 8];
      float4 c0 = *(const float4*)cwp;
      float4 c1 = *(const float4*)(cwp + 4);
      float wre = r4[0] * c0.x + r4[1] * c0.z + r4[2] * c1.x + r4[3] * c1.z;
      float wim = r4[0] * c0.y + r4[1] * c0.w + r4[2] * c1.y + r4[3] * c1.w;
      float rr = xr[s] * wre - xi[s] * wim;
      xi[s] = xr[s] * wim + xi[s] * wre;
      xr[s] = rr;
    }
    fft64_r2n<1>(xr, xi);
#pragma unroll
    for (int h = 0; h < 64; h++)
      Fs[h * 33 + lane] = make_float2(xr[h], xi[h]);
  }
  __syncthreads();

  // ==== pass 4a: read spectrum row into registers (Hermitian pack) ====
#pragma unroll
  for (int k = 0; k < 33; k++) {
    float2 v = Fs[lane * 33 + k];
    if (k == 0 || k == 32) { xr[k] = v.x; xi[k] = 0.f; }
    else                   { xr[k] = 2.f * v.x; xi[k] = 2.f * v.y; }
  }
#pragma unroll
  for (int k = 33; k < 64; k++) { xr[k] = 0.f; xi[k] = 0.f; }
  __syncthreads();

  fft64_n2r<1>(xr, xi);

  // ==== re-stage img -> S (as X) for the gating term ====
#pragma unroll
  for (int t = 0; t < 16; t++) {
    const int idx = t * 64 + lane;
    float4 v = *(const float4*)&img[idx * 4];
    const int row = idx >> 4;
    const int col = (idx & 15) * 4;
    S[row * 65 + col + 0] = v.x;
    S[row * 65 + col + 1] = v.y;
    S[row * 65 + col + 2] = v.z;
    S[row * 65 + col + 3] = v.w;
  }
  __syncthreads();

  // ==== pass 4b: gating + add, write own row back into S ====
#pragma unroll
  for (int w = 0; w < 64; w++) {
    const int s = 8 * (w & 7) + (w >> 3);
    float4 sp = *(const float4*)&spw[(size_t)(lane * 64 + w) * 4];
    float sw = s4[0] * sp.x + s4[1] * sp.y + s4[2] * sp.z + s4[3] * sp.w;
    S[lane * 65 + w] = S[lane * 65 + w] * sw + xr[s];
  }
  __syncthreads();

  // ==== stage out: S -> coalesced global ====
#pragma unroll
  for (int t = 0; t < 16; t++) {
    const int idx = t * 64 + lane;
    const int row = idx >> 4;
    const int col = (idx & 15) * 4;
    float4 o;
    o.x = S[row * 65 + col + 0];
    o.y = S[row * 65 + col + 1];
    o.z = S[row * 65 + col + 2];
    o.w = S[row * 65 + col + 3];
    *(float4*)&img[idx * 4] = o;
  }
}

extern "C" void kernel_launch(void* const* d_in, const int* in_sizes, int n_in,
                              void* d_out, int out_size, void* d_ws, size_t ws_size,
                              hipStream_t stream) {
  const float* x          = (const float*)d_in[0];
  const float* w_pw1      = (const float*)d_in[1];
  const float* w_pw2      = (const float*)d_in[2];
  const float* star_scale = (const float*)d_in[3];
  const float* star_bias  = (const float*)d_in[4];
  const float* rw1w = (const float*)d_in[5];
  const float* rw1b = (const float*)d_in[6];
  const float* rwcw = (const float*)d_in[7];
  const float* rwcb = (const float*)d_in[8];
  const float* rw2w = (const float*)d_in[9];
  const float* rw2b = (const float*)d_in[10];
  const float* sp1w = (const float*)d_in[11];
  const float* sp1b = (const float*)d_in[12];
  const float* sp2w = (const float*)d_in[13];
  const float* sp2b = (const float*)d_in[14];
  const float* cw   = (const float*)d_in[15];
  const float* spw  = (const float*)d_in[16];

  if (ws_size < WS_END * sizeof(float)) return;
  const bool big_ws = (ws_size >= WS_END2 * sizeof(float));

  float* ws = (float*)d_ws;
  float* xp = ws + XP_OFF;
  unsigned short* r1    = (unsigned short*)(ws + R1_OFF);
  unsigned short* xT    = (unsigned short*)(ws + (big_ws ? XT2_OFF : XT_OFF));
  unsigned short* wconv = (unsigned short*)(ws + WCONV_OFF);
  unsigned short* wr1   = (unsigned short*)(ws + WR1_OFF);
  unsigned short* wrc   = (unsigned short*)(ws + WRC_OFF);
  unsigned short* wb1   = (unsigned short*)(ws + WB1_OFF);
  unsigned short* wb2   = (unsigned short*)(ws + WB2_OFF);
  float* meansum = ws + MEAN_OFF;
  float* agg     = ws + AGG_OFF;
  float* tap     = ws + TAP_OFF;
  float* route   = ws + ROUTE_OFF;
  float* sr      = ws + SR_OFF;
  float* out = (float*)d_out;

  hipMemsetAsync(meansum, 0, (4096 + 36864) * sizeof(float), stream);

  // bf16 prep
  xpose_bf16<<<dim3(128, 16, 16), 256, 0, stream>>>(x, xT);
  wconv_bf16<<<512, 256, 0, stream>>>(sp1w, wconv);
  cvt_bf16<<<2048, 256, 0, stream>>>(w_pw1, wb1, MEDC * DIMC);
  cvt_bf16<<<2048, 256, 0, stream>>>(w_pw2, wb2, DIMC * MEDC);
  cvt_bf16<<<512, 256, 0, stream>>>(rw1w, wr1, HRC * DIMC);
  cvt_bf16<<<256, 256, 0, stream>>>(rwcw, wrc, HRC * HRC);

  // routing branch (bf16 MFMA)
  gemm_bf16<1, 0><<<dim3(32, 2, 16), 256, 0, stream>>>(
      xT, wr1, rw1b, nullptr, r1, nullptr, nullptr, nullptr, DIMC, HRC);
  gemm_bf16<3, 0><<<dim3(32, 2, 16), 256, 0, stream>>>(
      r1, wrc, rwcb, nullptr, nullptr, meansum, nullptr, nullptr, HRC, HRC);
  route_softmax<<<dim3(4, 16), 256, 0, stream>>>(meansum, rw2w, rw2b, route);

  // spatial routing branch (bf16 MFMA conv, halo-LDS)
  conv3_mfma<<<dim3(32, 2, 16), 256, 0, stream>>>(xT, wconv, sp1b, agg);
  tap_compute<<<16, 256, 0, stream>>>(agg, tap);
  sproute_softmax<<<dim3(4, 16), 256, 0, stream>>>(tap, sp2w, sp2b, sr);

  // main path (bf16 MFMA). If xT is disjoint from the xp region (big_ws), pw1 can
  // read xT directly (ASRC0, bit-identical values); else fall back to f32 x (ASRC1)
  // because xT aliases xp (round-12 race).
  if (big_ws) {
    gemm_bf16<2, 0><<<dim3(32, 8, 16), 256, 0, stream>>>(
        xT, wb1, nullptr, xp, nullptr, nullptr, star_scale, star_bias, DIMC, MEDC);
  } else {
    gemm_bf16<2, 1><<<dim3(32, 8, 16), 256, 0, stream>>>(
        x, wb1, nullptr, xp, nullptr, nullptr, star_scale, star_bias, DIMC, MEDC);
  }
  fft_filter<<<8192, 128, 0, stream>>>(xp, route, sr, cw, spw);
  gemm_bf16<0, 1><<<dim3(32, 4, 16), 256, 0, stream>>>(
      xp, wb2, nullptr, out, nullptr, nullptr, nullptr, nullptr, MEDC, DIMC);
}